// Round 20
// baseline (315.120 us; speedup 1.0000x reference)
//
#include <hip/hip_runtime.h>
#include <hip/hip_bf16.h>
#include <cstdint>

// Problem constants (B=2,S=4096,D=2048,E=8,SH=2,F=512,K=2)
#define TOKENS   8192
#define D_DIM    2048
#define F_DIM    512
#define NE       8
#define NSH      2
#define NZ       10
#define OUT_ELEMS (TOKENS * D_DIM)

// pair bookkeeping: routed capacity padded to 128-row tiles, then shared pairs
#define RCAP     17408                  // sum ceil(c_e/128)*128 <= 16384+8*127
#define SH_BASE  RCAP
#define NPAIRS   (RCAP + 2 * TOKENS)    // 33792
#define MAX_RT   136                    // max routed 128-row M-tiles
// per-XCD caps (top-2 distinct => count_e <= 8192 => nt_e <= 64)
#define G1_CAP   640                    // 64*8 + 128 shared items (64-col tiles)
#define G2R_CAP  2048                   // 64*32 (64-col tiles)

typedef __attribute__((ext_vector_type(8))) short bf16x8;
typedef __attribute__((ext_vector_type(4))) float f32x4;

__device__ __forceinline__ short f2bf(float f) {
  union { float f; uint32_t u; } v; v.f = f;
  uint32_t r = (v.u + 0x7fffu + ((v.u >> 16) & 1u)) >> 16;
  return (short)r;
}
__device__ __forceinline__ float bf2f(short s) {
  union { float f; uint32_t u; } v; v.u = ((uint32_t)(uint16_t)s) << 16; return v.f;
}

__device__ __forceinline__ void gload_lds16(const void* g, void* l) {
  __builtin_amdgcn_global_load_lds(
      (const __attribute__((address_space(1))) unsigned int*)g,
      (__attribute__((address_space(3))) unsigned int*)l,
      16, 0, 0);
}

// ------ transpose-convert fp32 (R,C) -> bf16 (C,R), vectorized stores -------
__global__ void k_transpose(const float* __restrict__ ein,
                            const float* __restrict__ sin_,
                            short* __restrict__ out, int R, int C) {
  __shared__ float tile[64][33];
  int b = blockIdx.z;
  const float* in = (b < NE) ? (ein + (size_t)b * R * C)
                             : (sin_ + (size_t)(b - NE) * R * C);
  out += (size_t)b * R * C;
  int c0 = blockIdx.x * 32, r0 = blockIdx.y * 64;
  int id = threadIdx.x;
  int lc = id & 31, lr = id >> 5;
  #pragma unroll
  for (int i = 0; i < 8; i++) {
    int row = i * 8 + lr;
    tile[row][lc] = in[(size_t)(r0 + row) * C + c0 + lc];
  }
  __syncthreads();
  short4* out4 = (short4*)out;
  #pragma unroll
  for (int j = 0; j < 2; j++) {
    int s = j * 256 + id;
    int c = s >> 4, q = s & 15;
    short4 o;
    o.x = f2bf(tile[4 * q + 0][c]);
    o.y = f2bf(tile[4 * q + 1][c]);
    o.z = f2bf(tile[4 * q + 2][c]);
    o.w = f2bf(tile[4 * q + 3][c]);
    out4[(((size_t)(c0 + c) * R) + r0) / 4 + q] = o;
  }
}

// -------- router: wave-per-token, fp32 float4, exact top-2; writes xb bf16 --
__global__ __launch_bounds__(256) void k_router(
    const float* __restrict__ x, const float* __restrict__ rw,
    const float* __restrict__ rb, short* __restrict__ xb,
    int2* __restrict__ ti, float2* __restrict__ tg,
    int* __restrict__ pair_tok, float* __restrict__ pair_gate) {
  int gid = blockIdx.x * 256 + threadIdx.x;
  if (gid < RCAP) { pair_tok[gid] = 0; pair_gate[gid] = 0.f; }
  int wave = threadIdx.x >> 6;
  int lane = threadIdx.x & 63;
  int t = blockIdx.x * 4 + wave;
  const float4* xr = (const float4*)(x + (size_t)t * D_DIM);
  short4* xbr = (short4*)(xb + (size_t)t * D_DIM);
  const float4* rw4 = (const float4*)rw;
  float acc[NE];
  #pragma unroll
  for (int e = 0; e < NE; e++) acc[e] = 0.f;
  #pragma unroll
  for (int it = 0; it < D_DIM / 4 / 64; it++) {
    int i = it * 64 + lane;
    float4 v = xr[i];
    short4 o;
    o.x = f2bf(v.x); o.y = f2bf(v.y); o.z = f2bf(v.z); o.w = f2bf(v.w);
    xbr[i] = o;
    #pragma unroll
    for (int e = 0; e < NE; e++) {
      float4 w = rw4[e * (D_DIM / 4) + i];
      acc[e] += v.x * w.x + v.y * w.y + v.z * w.z + v.w * w.w;
    }
  }
  #pragma unroll
  for (int e = 0; e < NE; e++) {
    #pragma unroll
    for (int off = 32; off > 0; off >>= 1) acc[e] += __shfl_xor(acc[e], off);
  }
  if (lane == 0) {
    float lg[NE];
    #pragma unroll
    for (int e = 0; e < NE; e++) lg[e] = acc[e] + rb[e];
    int i0 = 0;
    #pragma unroll
    for (int e = 1; e < NE; e++) if (lg[e] > lg[i0]) i0 = e;
    int i1 = (i0 == 0) ? 1 : 0;
    #pragma unroll
    for (int e = 0; e < NE; e++) if (e != i0 && e != i1 && lg[e] > lg[i1]) i1 = e;
    float e1 = __expf(lg[i1] - lg[i0]);
    float inv = 1.f / (1.f + e1);
    ti[t] = make_int2(i0, i1);
    tg[t] = make_float2(inv, e1 * inv);
  }
}

// ------ count + tile table (parallel fill) + aux loss (single block) --------
__global__ __launch_bounds__(1024) void k_count(
    const int2* __restrict__ ti, int* __restrict__ meta,
    int* __restrict__ tile_z, int* __restrict__ tile_row,
    float* __restrict__ out_loss) {
  __shared__ int cnt[NE + 2];
  __shared__ int tb[NE + 1];
  __shared__ int sb[NE];
  if (threadIdx.x < NE + 2) cnt[threadIdx.x] = 0;
  __syncthreads();
  int loc[NE]; int l0 = 0, l1 = 0;
  #pragma unroll
  for (int e = 0; e < NE; e++) loc[e] = 0;
  for (int t = threadIdx.x; t < TOKENS; t += 1024) {
    int2 ii = ti[t];
    loc[ii.x]++; loc[ii.y]++;
    l0 += (ii.x == 0); l1 += (ii.y == 1);
  }
  #pragma unroll
  for (int e = 0; e < NE; e++) if (loc[e]) atomicAdd(&cnt[e], loc[e]);
  if (l0) atomicAdd(&cnt[NE], l0);
  if (l1) atomicAdd(&cnt[NE + 1], l1);
  __syncthreads();
  if (threadIdx.x == 0) {
    int base = 0, nrt = 0;
    #pragma unroll
    for (int e = 0; e < NE; e++) {
      int c = cnt[e];
      meta[e] = c;
      meta[19 + e] = base;
      meta[8 + e] = 0;                       // cursor
      int nt = (c + 127) >> 7;
      meta[40 + e] = nrt;                    // tile-slot base
      meta[48 + e] = nt;                     // tile count
      sb[e] = base; tb[e] = nrt;
      nrt += nt; base += nt * 128;
    }
    tb[NE] = nrt;
    meta[18] = nrt;
    float p0 = (float)cnt[NE] / 16384.0f + 1e-8f;
    float p1 = (float)cnt[NE + 1] / 16384.0f + 1e-8f;
    float rest = 6.0f * (1e-8f * logf(1e-8f));
    out_loss[0] = -(p0 * logf(p0) + p1 * logf(p1) + rest);
  }
  __syncthreads();
  int s = threadIdx.x;
  if (s < tb[NE]) {
    int e = 0;
    #pragma unroll
    for (int k = 1; k < NE; k++) if (s >= tb[k]) e = k;
    tile_z[s] = e;
    tile_row[s] = sb[e] + (s - tb[e]) * 128;
  }
  if (s < 128) {
    tile_z[MAX_RT + s] = NE + (s >> 6);
    tile_row[MAX_RT + s] = SH_BASE + (s >> 6) * TOKENS + (s & 63) * 128;
  }
}

// ---------------- assignment: ballot-scan within wave + inverse map ---------
__global__ __launch_bounds__(256) void k_assign(
    const int2* __restrict__ ti, const float2* __restrict__ tg,
    int* __restrict__ meta, int* __restrict__ pair_tok, float* __restrict__ pair_gate,
    int2* __restrict__ pos) {
  int t = blockIdx.x * 256 + threadIdx.x;
  int lane = threadIdx.x & 63;
  int2 ii = ti[t];
  float2 gg = tg[t];
  int2 mypos;
  unsigned long long below = (1ull << lane) - 1ull;
  #pragma unroll
  for (int e = 0; e < NE; e++) {
    unsigned long long m0 = __ballot(ii.x == e);
    unsigned long long m1 = __ballot(ii.y == e);
    unsigned c = __popcll(m0) + __popcll(m1);
    unsigned base = 0;
    if (lane == 0 && c) base = atomicAdd((unsigned*)&meta[8 + e], c);
    base = __shfl((int)base, 0);
    int seg = meta[19 + e];
    if (ii.x == e) {
      int p = seg + base + __popcll(m0 & below);
      pair_tok[p] = t; pair_gate[p] = gg.x; mypos.x = p;
    }
    if (ii.y == e) {
      int p = seg + base + __popcll(m0) + __popcll(m1 & below);
      pair_tok[p] = t; pair_gate[p] = gg.y; mypos.y = p;
    }
  }
  pos[t] = mypos;
  pair_tok[SH_BASE + t] = t;            pair_gate[SH_BASE + t] = 1.f;
  pair_tok[SH_BASE + TOKENS + t] = t;   pair_gate[SH_BASE + TOKENS + t] = 1.f;
}

// ============================================================================
// GEMM cores: r17 skeleton (body order + compile-time-buffer unroll),
// 128x64 tiles EVERYWHERE (r19-proven): A 128rows + B 64rows, dbuf LDS 48KB
// -> 3 blocks/CU. 6 gloads/thread/tile -> vmcnt(6) ledger ({t:6,t+1:6}).
// 16 MFMA + 12 ds_read per tile. XOR &7 swizzle (0 conflicts), XCD pinning.
// ============================================================================

#define GBODY_N2(T_, BUF_, NTV, STAGE_MACRO)                              \
    if ((T_) + 1 < (NTV)) asm volatile("s_waitcnt vmcnt(6)" ::: "memory");\
    else                  asm volatile("s_waitcnt vmcnt(0)" ::: "memory");\
    __builtin_amdgcn_s_barrier();                                         \
    asm volatile("" ::: "memory");                                        \
    {                                                                     \
      bf16x8 af0[4], bf0[2], af1[4], bf1[2];                              \
      _Pragma("unroll") for (int m = 0; m < 4; m++) {                     \
        af0[m] = *(const bf16x8*)&As[BUF_][rowAo[m] + slt0];              \
        af1[m] = *(const bf16x8*)&As[BUF_][rowAo[m] + slt1];              \
      }                                                                   \
      _Pragma("unroll") for (int n = 0; n < 2; n++) {                     \
        bf0[n] = *(const bf16x8*)&Bs[BUF_][rowBo[n] + slt0];              \
        bf1[n] = *(const bf16x8*)&Bs[BUF_][rowBo[n] + slt1];              \
      }                                                                   \
      asm volatile("s_waitcnt lgkmcnt(0)" ::: "memory");                  \
      __builtin_amdgcn_sched_barrier(0);                                  \
      __builtin_amdgcn_s_barrier();                                       \
      asm volatile("" ::: "memory");                                      \
      if ((T_) + 2 < (NTV)) STAGE_MACRO(BUF_, (T_) + 2);                  \
      __builtin_amdgcn_s_setprio(1);                                      \
      _Pragma("unroll") for (int m = 0; m < 4; m++)                       \
        _Pragma("unroll") for (int n = 0; n < 2; n++)                     \
          acc[m][n] = __builtin_amdgcn_mfma_f32_16x16x32_bf16(            \
              af0[m], bf0[n], acc[m][n], 0, 0, 0);                        \
      _Pragma("unroll") for (int m = 0; m < 4; m++)                       \
        _Pragma("unroll") for (int n = 0; n < 2; n++)                     \
          acc[m][n] = __builtin_amdgcn_mfma_f32_16x16x32_bf16(            \
              af1[m], bf1[n], acc[m][n], 0, 0, 0);                        \
      __builtin_amdgcn_s_setprio(0);                                      \
    }

// ---------------- GEMM1: H[p] = gelu(x[tok(p)]@W1[z]+b1)*gate ---------------
// 128x64 tiles, F=512 -> 8 bn. grid 8*G1_CAP, XCD-pinned. 3 blocks/CU.
__global__ __launch_bounds__(256, 3) void k_gemm1(
    const short* __restrict__ xb, const short* __restrict__ w1t,
    const float* __restrict__ eb1, const float* __restrict__ sb1,
    const int* __restrict__ meta, const int* __restrict__ tile_z,
    const int* __restrict__ tile_row, const int* __restrict__ pair_tok,
    const float* __restrict__ pair_gate, short* __restrict__ H) {
  const int l = blockIdx.x;
  const int xcd = l & 7;
  const int i = l >> 3;
  const int ntx = meta[48 + xcd];
  int slot, bn;
  if (i < ntx * 8) {
    slot = meta[40 + xcd] + (i >> 3); bn = i & 7;
  } else {
    int j = i - ntx * 8;
    if (j >= 128) return;
    int js = xcd * 128 + j;                // 1024 shared items, 128 per XCD
    slot = MAX_RT + (js >> 3); bn = js & 7;
  }
  const int z = tile_z[slot];
  const int row0 = tile_row[slot];
  __shared__ __align__(16) short As[2][8192];
  __shared__ __align__(16) short Bs[2][4096];
  const int tid = threadIdx.x;
  const int lane = tid & 63;
  const int wv = tid >> 6;
  const int wm = wv >> 1, wn = wv & 1;

  const short* asrc[4]; const short* bsrc[2];
  {
    const short* wb = w1t + (size_t)z * F_DIM * D_DIM;
    int shtok = 0;
    if (slot >= MAX_RT) {
      shtok = row0 - SH_BASE;
      if (shtok >= TOKENS) shtok -= TOKENS;
    }
    #pragma unroll
    for (int i2 = 0; i2 < 4; i2++) {
      int id = i2 * 256 + tid;
      int row = id >> 3, c = id & 7;
      int kc = ((c ^ (row & 7)) << 3);
      int arow = (slot < MAX_RT) ? pair_tok[row0 + row] : (shtok + row);
      asrc[i2] = xb + (size_t)arow * D_DIM + kc;
    }
    #pragma unroll
    for (int i2 = 0; i2 < 2; i2++) {
      int id = i2 * 256 + tid;
      int row = id >> 3, c = id & 7;     // row 0..63
      int kc = ((c ^ (row & 7)) << 3);
      bsrc[i2] = wb + (size_t)(bn * 64 + row) * D_DIM + kc;
    }
  }

  const int slt0 = (((lane >> 4)) ^ (lane & 7)) << 3;
  const int slt1 = ((4 + (lane >> 4)) ^ (lane & 7)) << 3;
  int rowAo[4], rowBo[2];
  #pragma unroll
  for (int m = 0; m < 4; m++)
    rowAo[m] = (wm * 64 + m * 16 + (lane & 15)) * 64;
  #pragma unroll
  for (int n = 0; n < 2; n++)
    rowBo[n] = (wn * 32 + n * 16 + (lane & 15)) * 64;

  f32x4 acc[4][2];
  #pragma unroll
  for (int m = 0; m < 4; m++)
    #pragma unroll
    for (int n = 0; n < 2; n++) acc[m][n] = (f32x4)(0.f);

  #define STAGE1(BUF, TT) do {                                            \
      int k0_ = (TT) * 64;                                                \
      _Pragma("unroll") for (int i2 = 0; i2 < 4; i2++)                    \
        gload_lds16(asrc[i2] + k0_, &As[BUF][(i2 * 256 + tid) * 8]);      \
      _Pragma("unroll") for (int i2 = 0; i2 < 2; i2++)                    \
        gload_lds16(bsrc[i2] + k0_, &Bs[BUF][(i2 * 256 + tid) * 8]);      \
    } while (0)

  STAGE1(0, 0);
  STAGE1(1, 1);

  const int NT = D_DIM / 64;   // 32 (even)
  for (int t = 0; t < NT; t += 2) {
    GBODY_N2(t,     0, NT, STAGE1);
    GBODY_N2(t + 1, 1, NT, STAGE1);
  }
  #undef STAGE1

  const float* b1 = (z < NE) ? (eb1 + z * F_DIM) : (sb1 + (size_t)(z - NE) * F_DIM);
  #pragma unroll
  for (int m = 0; m < 4; m++) {
    #pragma unroll
    for (int r = 0; r < 4; r++) {
      int row = wm * 64 + m * 16 + (lane >> 4) * 4 + r;
      float g = pair_gate[row0 + row];
      #pragma unroll
      for (int n = 0; n < 2; n++) {
        int col = bn * 64 + wn * 32 + n * 16 + (lane & 15);
        float c = acc[m][n][r] + b1[col];
        float h = 0.5f * c * (1.0f + erff(c * 0.70710678118654752440f));
        H[(size_t)(row0 + row) * F_DIM + col] = f2bf(h * g);
      }
    }
  }
}

// ---------------- GEMM2 routed: Yr[p] = H[p] @ W2t[z]  (K=512) --------------
// 128x64 tiles, D=2048 -> 32 bn. grid 8*G2R_CAP. 3 blocks/CU.
__global__ __launch_bounds__(256, 3) void k_gemm2r(
    const short* __restrict__ Hb, const short* __restrict__ w2t,
    const int* __restrict__ meta, const int* __restrict__ tile_z,
    const int* __restrict__ tile_row, short* __restrict__ Yr) {
  const int l = blockIdx.x;
  const int xcd = l & 7;
  const int i = l >> 3;
  const int ntx = meta[48 + xcd];
  if (i >= ntx * 32) return;
  const int slot = meta[40 + xcd] + (i >> 5);
  const int bn = i & 31;
  const int z = tile_z[slot];
  const int row0 = tile_row[slot];
  __shared__ __align__(16) short As[2][8192];
  __shared__ __align__(16) short Bs[2][4096];
  const int tid = threadIdx.x;
  const int lane = tid & 63;
  const int wv = tid >> 6;
  const int wm = wv >> 1, wn = wv & 1;

  const short* asrc[4]; const short* bsrc[2];
  {
    const short* Bb = w2t + (size_t)z * D_DIM * F_DIM;
    #pragma unroll
    for (int i2 = 0; i2 < 4; i2++) {
      int id = i2 * 256 + tid;
      int row = id >> 3, c = id & 7;
      int kc = ((c ^ (row & 7)) << 3);
      asrc[i2] = Hb + (size_t)(row0 + row) * F_DIM + kc;
    }
    #pragma unroll
    for (int i2 = 0; i2 < 2; i2++) {
      int id = i2 * 256 + tid;
      int row = id >> 3, c = id & 7;
      int kc = ((c ^ (row & 7)) << 3);
      bsrc[i2] = Bb + (size_t)(bn * 64 + row) * F_DIM + kc;
    }
  }

  const int slt0 = (((lane >> 4)) ^ (lane & 7)) << 3;
  const int slt1 = ((4 + (lane >> 4)) ^ (lane & 7)) << 3;
  int rowAo[4], rowBo[2];
  #pragma unroll
  for (int m = 0; m < 4; m++)
    rowAo[m] = (wm * 64 + m * 16 + (lane & 15)) * 64;
  #pragma unroll
  for (int n = 0; n < 2; n++)
    rowBo[n] = (wn * 32 + n * 16 + (lane & 15)) * 64;

  f32x4 acc[4][2];
  #pragma unroll
  for (int m = 0; m < 4; m++)
    #pragma unroll
    for (int n = 0; n < 2; n++) acc[m][n] = (f32x4)(0.f);

  #define STAGE2R(BUF, TT) do {                                           \
      int k0_ = (TT) * 64;                                                \
      _Pragma("unroll") for (int i2 = 0; i2 < 4; i2++)                    \
        gload_lds16(asrc[i2] + k0_, &As[BUF][(i2 * 256 + tid) * 8]);      \
      _Pragma("unroll") for (int i2 = 0; i2 < 2; i2++)                    \
        gload_lds16(bsrc[i2] + k0_, &Bs[BUF][(i2 * 256 + tid) * 8]);      \
    } while (0)

  STAGE2R(0, 0);
  STAGE2R(1, 1);

  const int NT = F_DIM / 64;   // 8 (even)
  for (int t = 0; t < NT; t += 2) {
    GBODY_N2(t,     0, NT, STAGE2R);
    GBODY_N2(t + 1, 1, NT, STAGE2R);
  }
  #undef STAGE2R

  #pragma unroll
  for (int m = 0; m < 4; m++) {
    #pragma unroll
    for (int r = 0; r < 4; r++) {
      int row = wm * 64 + m * 16 + (lane >> 4) * 4 + r;
      #pragma unroll
      for (int n = 0; n < 2; n++) {
        int col = bn * 64 + wn * 32 + n * 16 + (lane & 15);
        Yr[(size_t)(row0 + row) * D_DIM + col] = f2bf(acc[m][n][r]);
      }
    }
  }
}

// -------- GEMM2 shared (K=1024) + fused combine: out = shared + biases + Yr -
// NOW 128x64 tiles (r19 geometry): grid 2048 flat, XCD-pinned; 3 blocks/CU.
__global__ __launch_bounds__(256, 3) void k_gemm2s(
    const short* __restrict__ Hb, const short* __restrict__ w2t,
    const int2* __restrict__ ti, const float2* __restrict__ tg,
    const float* __restrict__ eb2, const float* __restrict__ sb2,
    const short* __restrict__ Yr, const int2* __restrict__ pos,
    float* __restrict__ out) {
  const int l = blockIdx.x;
  const int js = (l & 7) * 256 + (l >> 3);   // 2048 items, 256 per XCD
  const int t0 = (js >> 5) * 128;            // token-tile
  const int bn = js & 31;                    // 64-col tile of D=2048
  __shared__ __align__(16) short As[2][8192];
  __shared__ __align__(16) short Bs[2][4096];
  const int tid = threadIdx.x;
  const int lane = tid & 63;
  const int wv = tid >> 6;
  const int wm = wv >> 1, wn = wv & 1;

  size_t aoff[4], boff[2];
  #pragma unroll
  for (int i2 = 0; i2 < 4; i2++) {
    int id = i2 * 256 + tid;
    int row = id >> 3, c = id & 7;
    int kc = ((c ^ (row & 7)) << 3);
    aoff[i2] = (size_t)row * F_DIM + kc;
  }
  #pragma unroll
  for (int i2 = 0; i2 < 2; i2++) {
    int id = i2 * 256 + tid;
    int row = id >> 3, c = id & 7;
    int kc = ((c ^ (row & 7)) << 3);
    boff[i2] = (size_t)(bn * 64 + row) * F_DIM + kc;
  }
  const short* Abase0 = Hb + (size_t)(SH_BASE + t0) * F_DIM;
  const short* Bbase0 = w2t + (size_t)NE * D_DIM * F_DIM;

  const int slt0 = (((lane >> 4)) ^ (lane & 7)) << 3;
  const int slt1 = ((4 + (lane >> 4)) ^ (lane & 7)) << 3;
  int rowAo[4], rowBo[2];
  #pragma unroll
  for (int m = 0; m < 4; m++)
    rowAo[m] = (wm * 64 + m * 16 + (lane & 15)) * 64;
  #pragma unroll
  for (int n = 0; n < 2; n++)
    rowBo[n] = (wn * 32 + n * 16 + (lane & 15)) * 64;

  f32x4 acc[4][2];
  #pragma unroll
  for (int m = 0; m < 4; m++)
    #pragma unroll
    for (int n = 0; n < 2; n++) acc[m][n] = (f32x4)(0.f);

  #define STAGE2S(BUF, TT) do {                                           \
      int kcol_ = ((TT) * 64) & (F_DIM - 1);                              \
      const short* Ab_ = Abase0;                                          \
      const short* Bb_ = Bbase0;                                          \
      if ((TT) >= 8) {                                                    \
        Ab_ += (size_t)TOKENS * F_DIM;                                    \
        Bb_ += (size_t)D_DIM * F_DIM;                                     \
      }                                                                   \
      _Pragma("unroll") for (int i2 = 0; i2 < 4; i2++)                    \
        gload_lds16(Ab_ + aoff[i2] + kcol_, &As[BUF][(i2 * 256 + tid) * 8]); \
      _Pragma("unroll") for (int i2 = 0; i2 < 2; i2++)                    \
        gload_lds16(Bb_ + boff[i2] + kcol_, &Bs[BUF][(i2 * 256 + tid) * 8]); \
    } while (0)

  STAGE2S(0, 0);
  STAGE2S(1, 1);

  const int NT = 16;
  for (int t = 0; t < NT; t += 2) {
    GBODY_N2(t,     0, NT, STAGE2S);
    GBODY_N2(t + 1, 1, NT, STAGE2S);
  }
  #undef STAGE2S

  #pragma unroll
  for (int m = 0; m < 4; m++) {
    #pragma unroll
    for (int r = 0; r < 4; r++) {
      int row = t0 + wm * 64 + m * 16 + (lane >> 4) * 4 + r;
      int2 ii = ti[row]; float2 gg = tg[row];
      int2 p = pos[row];
      #pragma unroll
      for (int n = 0; n < 2; n++) {
        int col = bn * 64 + wn * 32 + n * 16 + (lane & 15);
        float v = acc[m][n][r]
                + gg.x * eb2[(size_t)ii.x * D_DIM + col]
                + gg.y * eb2[(size_t)ii.y * D_DIM + col]
                + sb2[col] + sb2[D_DIM + col]
                + bf2f(Yr[(size_t)p.x * D_DIM + col])
                + bf2f(Yr[(size_t)p.y * D_DIM + col]);
        out[(size_t)row * D_DIM + col] = v;
      }
    }
  }
}

// ---------------------------------------------------------------------------
extern "C" void kernel_launch(void* const* d_in, const int* in_sizes, int n_in,
                              void* d_out, int out_size, void* d_ws, size_t ws_size,
                              hipStream_t stream) {
  (void)in_sizes; (void)n_in; (void)out_size; (void)ws_size;
  const float* x        = (const float*)d_in[0];
  const float* router_w = (const float*)d_in[1];
  const float* router_b = (const float*)d_in[2];
  const float* ew1      = (const float*)d_in[3];
  const float* eb1      = (const float*)d_in[4];
  const float* ew2      = (const float*)d_in[5];
  const float* eb2      = (const float*)d_in[6];
  const float* sw1      = (const float*)d_in[7];
  const float* sb1      = (const float*)d_in[8];
  const float* sw2      = (const float*)d_in[9];
  const float* sb2      = (const float*)d_in[10];
  float* out = (float*)d_out;

  // workspace layout (Yr aliases xb+w1t+overhang; dead after k_gemm1):
  //   w2t 20.97MB | Hbuf 34.6MB | small ~0.6MB | xb 33.55MB | w1t 20.97MB |
  //   Yr-overhang ~17MB  => total ~128MB
  char* ws = (char*)d_ws;
  short*  w2t       = (short*)ws;
  short*  Hbuf      = w2t + (size_t)NZ * D_DIM * F_DIM;
  int2*   ti        = (int2*)(Hbuf + (size_t)NPAIRS * F_DIM);
  float2* tg        = (float2*)(ti + TOKENS);
  int2*   pos       = (int2*)(tg + TOKENS);
  int*    pair_tok  = (int*)(pos + TOKENS);
  float*  pair_gate = (float*)(pair_tok + NPAIRS);
  int*    meta      = (int*)(pair_gate + NPAIRS);
  int*    tile_z    = meta + 64;
  int*    tile_row  = tile_z + 512;
  short*  xb        = (short*)(((uintptr_t)(tile_row + 512) + 255) & ~(uintptr_t)255);
  short*  w1t       = xb + (size_t)TOKENS * D_DIM;
  short*  Yr        = xb;   // alias (valid after k_gemm1 completes)

  k_transpose<<<dim3(F_DIM / 32, D_DIM / 64, NZ), 256, 0, stream>>>(
      ew1, sw1, w1t, D_DIM, F_DIM);
  k_transpose<<<dim3(D_DIM / 32, F_DIM / 64, NZ), 256, 0, stream>>>(
      ew2, sw2, w2t, F_DIM, D_DIM);

  k_router<<<TOKENS / 4, 256, 0, stream>>>(x, router_w, router_b, xb, ti, tg,
                                           pair_tok, pair_gate);
  k_count<<<1, 1024, 0, stream>>>(ti, meta, tile_z, tile_row, out + OUT_ELEMS);
  k_assign<<<TOKENS / 256, 256, 0, stream>>>(ti, tg, meta, pair_tok, pair_gate, pos);

  k_gemm1<<<8 * G1_CAP, 256, 0, stream>>>(
      xb, w1t, eb1, sb1, meta, tile_z, tile_row, pair_tok, pair_gate, Hbuf);
  k_gemm2r<<<8 * G2R_CAP, 256, 0, stream>>>(
      Hbuf, w2t, meta, tile_z, tile_row, Yr);
  k_gemm2s<<<2048, 256, 0, stream>>>(
      Hbuf, w2t, ti, tg, eb2, sb2, Yr, pos, out);
}

// Round 21
// 309.420 us; speedup vs baseline: 1.0184x; 1.0184x over previous
//
#include <hip/hip_runtime.h>
#include <hip/hip_bf16.h>
#include <cstdint>

// Problem constants (B=2,S=4096,D=2048,E=8,SH=2,F=512,K=2)
#define TOKENS   8192
#define D_DIM    2048
#define F_DIM    512
#define NE       8
#define NSH      2
#define NZ       10
#define OUT_ELEMS (TOKENS * D_DIM)

// pair bookkeeping: routed capacity padded to 128-row tiles, then shared pairs
#define RCAP     17408                  // sum ceil(c_e/128)*128 <= 16384+8*127
#define SH_BASE  RCAP
#define NPAIRS   (RCAP + 2 * TOKENS)    // 33792
#define MAX_RT   136                    // max routed 128-row M-tiles
// per-XCD caps (top-2 distinct => count_e <= 8192 => nt_e <= 64)
#define G1_CAP   640                    // 64*8 + 128 shared items (64-col tiles)
#define G2R_CAP  2048                   // 64*32 (64-col tiles)

typedef __attribute__((ext_vector_type(8))) short bf16x8;
typedef __attribute__((ext_vector_type(4))) float f32x4;

__device__ __forceinline__ short f2bf(float f) {
  union { float f; uint32_t u; } v; v.f = f;
  uint32_t r = (v.u + 0x7fffu + ((v.u >> 16) & 1u)) >> 16;
  return (short)r;
}
__device__ __forceinline__ float bf2f(short s) {
  union { float f; uint32_t u; } v; v.u = ((uint32_t)(uint16_t)s) << 16; return v.f;
}

__device__ __forceinline__ void gload_lds16(const void* g, void* l) {
  __builtin_amdgcn_global_load_lds(
      (const __attribute__((address_space(1))) unsigned int*)g,
      (__attribute__((address_space(3))) unsigned int*)l,
      16, 0, 0);
}

// ------ transpose-convert fp32 (R,C) -> bf16 (C,R), vectorized stores -------
__global__ void k_transpose(const float* __restrict__ ein,
                            const float* __restrict__ sin_,
                            short* __restrict__ out, int R, int C) {
  __shared__ float tile[64][33];
  int b = blockIdx.z;
  const float* in = (b < NE) ? (ein + (size_t)b * R * C)
                             : (sin_ + (size_t)(b - NE) * R * C);
  out += (size_t)b * R * C;
  int c0 = blockIdx.x * 32, r0 = blockIdx.y * 64;
  int id = threadIdx.x;
  int lc = id & 31, lr = id >> 5;
  #pragma unroll
  for (int i = 0; i < 8; i++) {
    int row = i * 8 + lr;
    tile[row][lc] = in[(size_t)(r0 + row) * C + c0 + lc];
  }
  __syncthreads();
  short4* out4 = (short4*)out;
  #pragma unroll
  for (int j = 0; j < 2; j++) {
    int s = j * 256 + id;
    int c = s >> 4, q = s & 15;
    short4 o;
    o.x = f2bf(tile[4 * q + 0][c]);
    o.y = f2bf(tile[4 * q + 1][c]);
    o.z = f2bf(tile[4 * q + 2][c]);
    o.w = f2bf(tile[4 * q + 3][c]);
    out4[(((size_t)(c0 + c) * R) + r0) / 4 + q] = o;
  }
}

// -------- router: wave-per-token, fp32 float4, exact top-2; writes xb bf16 --
__global__ __launch_bounds__(256) void k_router(
    const float* __restrict__ x, const float* __restrict__ rw,
    const float* __restrict__ rb, short* __restrict__ xb,
    int2* __restrict__ ti, float2* __restrict__ tg,
    int* __restrict__ pair_tok, float* __restrict__ pair_gate) {
  int gid = blockIdx.x * 256 + threadIdx.x;
  if (gid < RCAP) { pair_tok[gid] = 0; pair_gate[gid] = 0.f; }
  int wave = threadIdx.x >> 6;
  int lane = threadIdx.x & 63;
  int t = blockIdx.x * 4 + wave;
  const float4* xr = (const float4*)(x + (size_t)t * D_DIM);
  short4* xbr = (short4*)(xb + (size_t)t * D_DIM);
  const float4* rw4 = (const float4*)rw;
  float acc[NE];
  #pragma unroll
  for (int e = 0; e < NE; e++) acc[e] = 0.f;
  #pragma unroll
  for (int it = 0; it < D_DIM / 4 / 64; it++) {
    int i = it * 64 + lane;
    float4 v = xr[i];
    short4 o;
    o.x = f2bf(v.x); o.y = f2bf(v.y); o.z = f2bf(v.z); o.w = f2bf(v.w);
    xbr[i] = o;
    #pragma unroll
    for (int e = 0; e < NE; e++) {
      float4 w = rw4[e * (D_DIM / 4) + i];
      acc[e] += v.x * w.x + v.y * w.y + v.z * w.z + v.w * w.w;
    }
  }
  #pragma unroll
  for (int e = 0; e < NE; e++) {
    #pragma unroll
    for (int off = 32; off > 0; off >>= 1) acc[e] += __shfl_xor(acc[e], off);
  }
  if (lane == 0) {
    float lg[NE];
    #pragma unroll
    for (int e = 0; e < NE; e++) lg[e] = acc[e] + rb[e];
    int i0 = 0;
    #pragma unroll
    for (int e = 1; e < NE; e++) if (lg[e] > lg[i0]) i0 = e;
    int i1 = (i0 == 0) ? 1 : 0;
    #pragma unroll
    for (int e = 0; e < NE; e++) if (e != i0 && e != i1 && lg[e] > lg[i1]) i1 = e;
    float e1 = __expf(lg[i1] - lg[i0]);
    float inv = 1.f / (1.f + e1);
    ti[t] = make_int2(i0, i1);
    tg[t] = make_float2(inv, e1 * inv);
  }
}

// ------ count + tile table (parallel fill) + aux loss (single block) --------
__global__ __launch_bounds__(1024) void k_count(
    const int2* __restrict__ ti, int* __restrict__ meta,
    int* __restrict__ tile_z, int* __restrict__ tile_row,
    float* __restrict__ out_loss) {
  __shared__ int cnt[NE + 2];
  __shared__ int tb[NE + 1];
  __shared__ int sb[NE];
  if (threadIdx.x < NE + 2) cnt[threadIdx.x] = 0;
  __syncthreads();
  int loc[NE]; int l0 = 0, l1 = 0;
  #pragma unroll
  for (int e = 0; e < NE; e++) loc[e] = 0;
  for (int t = threadIdx.x; t < TOKENS; t += 1024) {
    int2 ii = ti[t];
    loc[ii.x]++; loc[ii.y]++;
    l0 += (ii.x == 0); l1 += (ii.y == 1);
  }
  #pragma unroll
  for (int e = 0; e < NE; e++) if (loc[e]) atomicAdd(&cnt[e], loc[e]);
  if (l0) atomicAdd(&cnt[NE], l0);
  if (l1) atomicAdd(&cnt[NE + 1], l1);
  __syncthreads();
  if (threadIdx.x == 0) {
    int base = 0, nrt = 0;
    #pragma unroll
    for (int e = 0; e < NE; e++) {
      int c = cnt[e];
      meta[e] = c;
      meta[19 + e] = base;
      meta[8 + e] = 0;                       // cursor
      int nt = (c + 127) >> 7;
      meta[40 + e] = nrt;                    // tile-slot base
      meta[48 + e] = nt;                     // tile count
      sb[e] = base; tb[e] = nrt;
      nrt += nt; base += nt * 128;
    }
    tb[NE] = nrt;
    meta[18] = nrt;
    float p0 = (float)cnt[NE] / 16384.0f + 1e-8f;
    float p1 = (float)cnt[NE + 1] / 16384.0f + 1e-8f;
    float rest = 6.0f * (1e-8f * logf(1e-8f));
    out_loss[0] = -(p0 * logf(p0) + p1 * logf(p1) + rest);
  }
  __syncthreads();
  int s = threadIdx.x;
  if (s < tb[NE]) {
    int e = 0;
    #pragma unroll
    for (int k = 1; k < NE; k++) if (s >= tb[k]) e = k;
    tile_z[s] = e;
    tile_row[s] = sb[e] + (s - tb[e]) * 128;
  }
  if (s < 128) {
    tile_z[MAX_RT + s] = NE + (s >> 6);
    tile_row[MAX_RT + s] = SH_BASE + (s >> 6) * TOKENS + (s & 63) * 128;
  }
}

// ---------------- assignment: ballot-scan within wave + inverse map ---------
__global__ __launch_bounds__(256) void k_assign(
    const int2* __restrict__ ti, const float2* __restrict__ tg,
    int* __restrict__ meta, int* __restrict__ pair_tok, float* __restrict__ pair_gate,
    int2* __restrict__ pos) {
  int t = blockIdx.x * 256 + threadIdx.x;
  int lane = threadIdx.x & 63;
  int2 ii = ti[t];
  float2 gg = tg[t];
  int2 mypos;
  unsigned long long below = (1ull << lane) - 1ull;
  #pragma unroll
  for (int e = 0; e < NE; e++) {
    unsigned long long m0 = __ballot(ii.x == e);
    unsigned long long m1 = __ballot(ii.y == e);
    unsigned c = __popcll(m0) + __popcll(m1);
    unsigned base = 0;
    if (lane == 0 && c) base = atomicAdd((unsigned*)&meta[8 + e], c);
    base = __shfl((int)base, 0);
    int seg = meta[19 + e];
    if (ii.x == e) {
      int p = seg + base + __popcll(m0 & below);
      pair_tok[p] = t; pair_gate[p] = gg.x; mypos.x = p;
    }
    if (ii.y == e) {
      int p = seg + base + __popcll(m0) + __popcll(m1 & below);
      pair_tok[p] = t; pair_gate[p] = gg.y; mypos.y = p;
    }
  }
  pos[t] = mypos;
  pair_tok[SH_BASE + t] = t;            pair_gate[SH_BASE + t] = 1.f;
  pair_tok[SH_BASE + TOKENS + t] = t;   pair_gate[SH_BASE + TOKENS + t] = 1.f;
}

// ============================================================================
// GEMM cores: r17 skeleton (body order + compile-time-buffer unroll), two
// geometries (r19 measured best = 308.8us):
//  - 128x64 tiles (gemm1/gemm2r): A 128rows + B 64rows, dbuf LDS 48KB ->
//    3 blocks/CU. 6 gloads/thread/tile -> vmcnt(6) ledger ({t:6,t+1:6}).
//  - 128x128 (gemm2s): 64KB LDS, vmcnt(8), 32 MFMA/tile (perfect fill:
//    1024 items / 512 slots; r20 proved 128x64 here REGRESSES).
// XOR &7 swizzle on 128B rows (0 conflicts), XCD expert pinning.
// ============================================================================

#define GBODY_N2(T_, BUF_, NTV, STAGE_MACRO)                              \
    if ((T_) + 1 < (NTV)) asm volatile("s_waitcnt vmcnt(6)" ::: "memory");\
    else                  asm volatile("s_waitcnt vmcnt(0)" ::: "memory");\
    __builtin_amdgcn_s_barrier();                                         \
    asm volatile("" ::: "memory");                                        \
    {                                                                     \
      bf16x8 af0[4], bf0[2], af1[4], bf1[2];                              \
      _Pragma("unroll") for (int m = 0; m < 4; m++) {                     \
        af0[m] = *(const bf16x8*)&As[BUF_][rowAo[m] + slt0];              \
        af1[m] = *(const bf16x8*)&As[BUF_][rowAo[m] + slt1];              \
      }                                                                   \
      _Pragma("unroll") for (int n = 0; n < 2; n++) {                     \
        bf0[n] = *(const bf16x8*)&Bs[BUF_][rowBo[n] + slt0];              \
        bf1[n] = *(const bf16x8*)&Bs[BUF_][rowBo[n] + slt1];              \
      }                                                                   \
      asm volatile("s_waitcnt lgkmcnt(0)" ::: "memory");                  \
      __builtin_amdgcn_sched_barrier(0);                                  \
      __builtin_amdgcn_s_barrier();                                       \
      asm volatile("" ::: "memory");                                      \
      if ((T_) + 2 < (NTV)) STAGE_MACRO(BUF_, (T_) + 2);                  \
      __builtin_amdgcn_s_setprio(1);                                      \
      _Pragma("unroll") for (int m = 0; m < 4; m++)                       \
        _Pragma("unroll") for (int n = 0; n < 2; n++)                     \
          acc[m][n] = __builtin_amdgcn_mfma_f32_16x16x32_bf16(            \
              af0[m], bf0[n], acc[m][n], 0, 0, 0);                        \
      _Pragma("unroll") for (int m = 0; m < 4; m++)                       \
        _Pragma("unroll") for (int n = 0; n < 2; n++)                     \
          acc[m][n] = __builtin_amdgcn_mfma_f32_16x16x32_bf16(            \
              af1[m], bf1[n], acc[m][n], 0, 0, 0);                        \
      __builtin_amdgcn_s_setprio(0);                                      \
    }

#define GBODY_N4(T_, BUF_, NTV, STAGE_MACRO)                              \
    if ((T_) + 1 < (NTV)) asm volatile("s_waitcnt vmcnt(8)" ::: "memory");\
    else                  asm volatile("s_waitcnt vmcnt(0)" ::: "memory");\
    __builtin_amdgcn_s_barrier();                                         \
    asm volatile("" ::: "memory");                                        \
    {                                                                     \
      bf16x8 af0[4], bf0[4], af1[4], bf1[4];                              \
      _Pragma("unroll") for (int m = 0; m < 4; m++) {                     \
        af0[m] = *(const bf16x8*)&As[BUF_][rowAo[m] + slt0];              \
        bf0[m] = *(const bf16x8*)&Bs[BUF_][rowBo[m] + slt0];              \
        af1[m] = *(const bf16x8*)&As[BUF_][rowAo[m] + slt1];              \
        bf1[m] = *(const bf16x8*)&Bs[BUF_][rowBo[m] + slt1];              \
      }                                                                   \
      asm volatile("s_waitcnt lgkmcnt(0)" ::: "memory");                  \
      __builtin_amdgcn_sched_barrier(0);                                  \
      __builtin_amdgcn_s_barrier();                                       \
      asm volatile("" ::: "memory");                                      \
      if ((T_) + 2 < (NTV)) STAGE_MACRO(BUF_, (T_) + 2);                  \
      __builtin_amdgcn_s_setprio(1);                                      \
      _Pragma("unroll") for (int m = 0; m < 4; m++)                       \
        _Pragma("unroll") for (int n = 0; n < 4; n++)                     \
          acc[m][n] = __builtin_amdgcn_mfma_f32_16x16x32_bf16(            \
              af0[m], bf0[n], acc[m][n], 0, 0, 0);                        \
      _Pragma("unroll") for (int m = 0; m < 4; m++)                       \
        _Pragma("unroll") for (int n = 0; n < 4; n++)                     \
          acc[m][n] = __builtin_amdgcn_mfma_f32_16x16x32_bf16(            \
              af1[m], bf1[n], acc[m][n], 0, 0, 0);                        \
      __builtin_amdgcn_s_setprio(0);                                      \
    }

// ---------------- GEMM1: H[p] = gelu(x[tok(p)]@W1[z]+b1)*gate ---------------
// 128x64 tiles, F=512 -> 8 bn. grid 8*G1_CAP, XCD-pinned. 3 blocks/CU.
__global__ __launch_bounds__(256, 3) void k_gemm1(
    const short* __restrict__ xb, const short* __restrict__ w1t,
    const float* __restrict__ eb1, const float* __restrict__ sb1,
    const int* __restrict__ meta, const int* __restrict__ tile_z,
    const int* __restrict__ tile_row, const int* __restrict__ pair_tok,
    const float* __restrict__ pair_gate, short* __restrict__ H) {
  const int l = blockIdx.x;
  const int xcd = l & 7;
  const int i = l >> 3;
  const int ntx = meta[48 + xcd];
  int slot, bn;
  if (i < ntx * 8) {
    slot = meta[40 + xcd] + (i >> 3); bn = i & 7;
  } else {
    int j = i - ntx * 8;
    if (j >= 128) return;
    int js = xcd * 128 + j;                // 1024 shared items, 128 per XCD
    slot = MAX_RT + (js >> 3); bn = js & 7;
  }
  const int z = tile_z[slot];
  const int row0 = tile_row[slot];
  __shared__ __align__(16) short As[2][8192];
  __shared__ __align__(16) short Bs[2][4096];
  const int tid = threadIdx.x;
  const int lane = tid & 63;
  const int wv = tid >> 6;
  const int wm = wv >> 1, wn = wv & 1;

  const short* asrc[4]; const short* bsrc[2];
  {
    const short* wb = w1t + (size_t)z * F_DIM * D_DIM;
    int shtok = 0;
    if (slot >= MAX_RT) {
      shtok = row0 - SH_BASE;
      if (shtok >= TOKENS) shtok -= TOKENS;
    }
    #pragma unroll
    for (int i2 = 0; i2 < 4; i2++) {
      int id = i2 * 256 + tid;
      int row = id >> 3, c = id & 7;
      int kc = ((c ^ (row & 7)) << 3);
      int arow = (slot < MAX_RT) ? pair_tok[row0 + row] : (shtok + row);
      asrc[i2] = xb + (size_t)arow * D_DIM + kc;
    }
    #pragma unroll
    for (int i2 = 0; i2 < 2; i2++) {
      int id = i2 * 256 + tid;
      int row = id >> 3, c = id & 7;     // row 0..63
      int kc = ((c ^ (row & 7)) << 3);
      bsrc[i2] = wb + (size_t)(bn * 64 + row) * D_DIM + kc;
    }
  }

  const int slt0 = (((lane >> 4)) ^ (lane & 7)) << 3;
  const int slt1 = ((4 + (lane >> 4)) ^ (lane & 7)) << 3;
  int rowAo[4], rowBo[2];
  #pragma unroll
  for (int m = 0; m < 4; m++)
    rowAo[m] = (wm * 64 + m * 16 + (lane & 15)) * 64;
  #pragma unroll
  for (int n = 0; n < 2; n++)
    rowBo[n] = (wn * 32 + n * 16 + (lane & 15)) * 64;

  f32x4 acc[4][2];
  #pragma unroll
  for (int m = 0; m < 4; m++)
    #pragma unroll
    for (int n = 0; n < 2; n++) acc[m][n] = (f32x4)(0.f);

  #define STAGE1(BUF, TT) do {                                            \
      int k0_ = (TT) * 64;                                                \
      _Pragma("unroll") for (int i2 = 0; i2 < 4; i2++)                    \
        gload_lds16(asrc[i2] + k0_, &As[BUF][(i2 * 256 + tid) * 8]);      \
      _Pragma("unroll") for (int i2 = 0; i2 < 2; i2++)                    \
        gload_lds16(bsrc[i2] + k0_, &Bs[BUF][(i2 * 256 + tid) * 8]);      \
    } while (0)

  STAGE1(0, 0);
  STAGE1(1, 1);

  const int NT = D_DIM / 64;   // 32 (even)
  for (int t = 0; t < NT; t += 2) {
    GBODY_N2(t,     0, NT, STAGE1);
    GBODY_N2(t + 1, 1, NT, STAGE1);
  }
  #undef STAGE1

  const float* b1 = (z < NE) ? (eb1 + z * F_DIM) : (sb1 + (size_t)(z - NE) * F_DIM);
  #pragma unroll
  for (int m = 0; m < 4; m++) {
    #pragma unroll
    for (int r = 0; r < 4; r++) {
      int row = wm * 64 + m * 16 + (lane >> 4) * 4 + r;
      float g = pair_gate[row0 + row];
      #pragma unroll
      for (int n = 0; n < 2; n++) {
        int col = bn * 64 + wn * 32 + n * 16 + (lane & 15);
        float c = acc[m][n][r] + b1[col];
        float h = 0.5f * c * (1.0f + erff(c * 0.70710678118654752440f));
        H[(size_t)(row0 + row) * F_DIM + col] = f2bf(h * g);
      }
    }
  }
}

// ---------------- GEMM2 routed: Yr[p] = H[p] @ W2t[z]  (K=512) --------------
// 128x64 tiles, D=2048 -> 32 bn. grid 8*G2R_CAP. 3 blocks/CU.
__global__ __launch_bounds__(256, 3) void k_gemm2r(
    const short* __restrict__ Hb, const short* __restrict__ w2t,
    const int* __restrict__ meta, const int* __restrict__ tile_z,
    const int* __restrict__ tile_row, short* __restrict__ Yr) {
  const int l = blockIdx.x;
  const int xcd = l & 7;
  const int i = l >> 3;
  const int ntx = meta[48 + xcd];
  if (i >= ntx * 32) return;
  const int slot = meta[40 + xcd] + (i >> 5);
  const int bn = i & 31;
  const int z = tile_z[slot];
  const int row0 = tile_row[slot];
  __shared__ __align__(16) short As[2][8192];
  __shared__ __align__(16) short Bs[2][4096];
  const int tid = threadIdx.x;
  const int lane = tid & 63;
  const int wv = tid >> 6;
  const int wm = wv >> 1, wn = wv & 1;

  const short* asrc[4]; const short* bsrc[2];
  {
    const short* Bb = w2t + (size_t)z * D_DIM * F_DIM;
    #pragma unroll
    for (int i2 = 0; i2 < 4; i2++) {
      int id = i2 * 256 + tid;
      int row = id >> 3, c = id & 7;
      int kc = ((c ^ (row & 7)) << 3);
      asrc[i2] = Hb + (size_t)(row0 + row) * F_DIM + kc;
    }
    #pragma unroll
    for (int i2 = 0; i2 < 2; i2++) {
      int id = i2 * 256 + tid;
      int row = id >> 3, c = id & 7;
      int kc = ((c ^ (row & 7)) << 3);
      bsrc[i2] = Bb + (size_t)(bn * 64 + row) * F_DIM + kc;
    }
  }

  const int slt0 = (((lane >> 4)) ^ (lane & 7)) << 3;
  const int slt1 = ((4 + (lane >> 4)) ^ (lane & 7)) << 3;
  int rowAo[4], rowBo[2];
  #pragma unroll
  for (int m = 0; m < 4; m++)
    rowAo[m] = (wm * 64 + m * 16 + (lane & 15)) * 64;
  #pragma unroll
  for (int n = 0; n < 2; n++)
    rowBo[n] = (wn * 32 + n * 16 + (lane & 15)) * 64;

  f32x4 acc[4][2];
  #pragma unroll
  for (int m = 0; m < 4; m++)
    #pragma unroll
    for (int n = 0; n < 2; n++) acc[m][n] = (f32x4)(0.f);

  #define STAGE2R(BUF, TT) do {                                           \
      int k0_ = (TT) * 64;                                                \
      _Pragma("unroll") for (int i2 = 0; i2 < 4; i2++)                    \
        gload_lds16(asrc[i2] + k0_, &As[BUF][(i2 * 256 + tid) * 8]);      \
      _Pragma("unroll") for (int i2 = 0; i2 < 2; i2++)                    \
        gload_lds16(bsrc[i2] + k0_, &Bs[BUF][(i2 * 256 + tid) * 8]);      \
    } while (0)

  STAGE2R(0, 0);
  STAGE2R(1, 1);

  const int NT = F_DIM / 64;   // 8 (even)
  for (int t = 0; t < NT; t += 2) {
    GBODY_N2(t,     0, NT, STAGE2R);
    GBODY_N2(t + 1, 1, NT, STAGE2R);
  }
  #undef STAGE2R

  #pragma unroll
  for (int m = 0; m < 4; m++) {
    #pragma unroll
    for (int r = 0; r < 4; r++) {
      int row = wm * 64 + m * 16 + (lane >> 4) * 4 + r;
      #pragma unroll
      for (int n = 0; n < 2; n++) {
        int col = bn * 64 + wn * 32 + n * 16 + (lane & 15);
        Yr[(size_t)(row0 + row) * D_DIM + col] = f2bf(acc[m][n][r]);
      }
    }
  }
}

// -------- GEMM2 shared (K=1024) + fused combine: out = shared + biases + Yr -
// 128x128 tiles (r19 config; perfect fill: 1024 items / 512 slots).
__global__ __launch_bounds__(256, 2) void k_gemm2s(
    const short* __restrict__ Hb, const short* __restrict__ w2t,
    const int2* __restrict__ ti, const float2* __restrict__ tg,
    const float* __restrict__ eb2, const float* __restrict__ sb2,
    const short* __restrict__ Yr, const int2* __restrict__ pos,
    float* __restrict__ out) {
  const int l = blockIdx.x;
  const int js = (l & 7) * 128 + (l >> 3);
  const int t0 = (js >> 4) * 128;
  const int bn = js & 15;
  __shared__ __align__(16) short As[2][8192];
  __shared__ __align__(16) short Bs[2][8192];
  const int tid = threadIdx.x;
  const int lane = tid & 63;
  const int wv = tid >> 6;
  const int wm = wv >> 1, wn = wv & 1;

  size_t aoff[4], boff[4];
  #pragma unroll
  for (int i2 = 0; i2 < 4; i2++) {
    int id = i2 * 256 + tid;
    int row = id >> 3, c = id & 7;
    int kc = ((c ^ (row & 7)) << 3);
    aoff[i2] = (size_t)row * F_DIM + kc;
    boff[i2] = (size_t)(bn * 128 + row) * F_DIM + kc;
  }
  const short* Abase0 = Hb + (size_t)(SH_BASE + t0) * F_DIM;
  const short* Bbase0 = w2t + (size_t)NE * D_DIM * F_DIM;

  const int slt0 = (((lane >> 4)) ^ (lane & 7)) << 3;
  const int slt1 = ((4 + (lane >> 4)) ^ (lane & 7)) << 3;
  int rowAo[4], rowBo[4];
  #pragma unroll
  for (int m = 0; m < 4; m++) {
    rowAo[m] = (wm * 64 + m * 16 + (lane & 15)) * 64;
    rowBo[m] = (wn * 64 + m * 16 + (lane & 15)) * 64;
  }

  f32x4 acc[4][4];
  #pragma unroll
  for (int m = 0; m < 4; m++)
    #pragma unroll
    for (int n = 0; n < 4; n++) acc[m][n] = (f32x4)(0.f);

  #define STAGE2S(BUF, TT) do {                                           \
      int kcol_ = ((TT) * 64) & (F_DIM - 1);                              \
      const short* Ab_ = Abase0;                                          \
      const short* Bb_ = Bbase0;                                          \
      if ((TT) >= 8) {                                                    \
        Ab_ += (size_t)TOKENS * F_DIM;                                    \
        Bb_ += (size_t)D_DIM * F_DIM;                                     \
      }                                                                   \
      _Pragma("unroll") for (int i2 = 0; i2 < 4; i2++) {                  \
        int id_ = i2 * 256 + tid;                                         \
        gload_lds16(Ab_ + aoff[i2] + kcol_, &As[BUF][id_ * 8]);           \
        gload_lds16(Bb_ + boff[i2] + kcol_, &Bs[BUF][id_ * 8]);           \
      }                                                                   \
    } while (0)

  STAGE2S(0, 0);
  STAGE2S(1, 1);

  const int NT = 16;
  for (int t = 0; t < NT; t += 2) {
    GBODY_N4(t,     0, NT, STAGE2S);
    GBODY_N4(t + 1, 1, NT, STAGE2S);
  }
  #undef STAGE2S

  #pragma unroll
  for (int m = 0; m < 4; m++) {
    #pragma unroll
    for (int r = 0; r < 4; r++) {
      int row = t0 + wm * 64 + m * 16 + (lane >> 4) * 4 + r;
      int2 ii = ti[row]; float2 gg = tg[row];
      int2 p = pos[row];
      #pragma unroll
      for (int n = 0; n < 4; n++) {
        int col = bn * 128 + wn * 64 + n * 16 + (lane & 15);
        float v = acc[m][n][r]
                + gg.x * eb2[(size_t)ii.x * D_DIM + col]
                + gg.y * eb2[(size_t)ii.y * D_DIM + col]
                + sb2[col] + sb2[D_DIM + col]
                + bf2f(Yr[(size_t)p.x * D_DIM + col])
                + bf2f(Yr[(size_t)p.y * D_DIM + col]);
        out[(size_t)row * D_DIM + col] = v;
      }
    }
  }
}

// ---------------------------------------------------------------------------
extern "C" void kernel_launch(void* const* d_in, const int* in_sizes, int n_in,
                              void* d_out, int out_size, void* d_ws, size_t ws_size,
                              hipStream_t stream) {
  (void)in_sizes; (void)n_in; (void)out_size; (void)ws_size;
  const float* x        = (const float*)d_in[0];
  const float* router_w = (const float*)d_in[1];
  const float* router_b = (const float*)d_in[2];
  const float* ew1      = (const float*)d_in[3];
  const float* eb1      = (const float*)d_in[4];
  const float* ew2      = (const float*)d_in[5];
  const float* eb2      = (const float*)d_in[6];
  const float* sw1      = (const float*)d_in[7];
  const float* sb1      = (const float*)d_in[8];
  const float* sw2      = (const float*)d_in[9];
  const float* sb2      = (const float*)d_in[10];
  float* out = (float*)d_out;

  // workspace layout (Yr aliases xb+w1t+overhang; dead after k_gemm1):
  //   w2t 20.97MB | Hbuf 34.6MB | small ~0.6MB | xb 33.55MB | w1t 20.97MB |
  //   Yr-overhang ~17MB  => total ~128MB
  char* ws = (char*)d_ws;
  short*  w2t       = (short*)ws;
  short*  Hbuf      = w2t + (size_t)NZ * D_DIM * F_DIM;
  int2*   ti        = (int2*)(Hbuf + (size_t)NPAIRS * F_DIM);
  float2* tg        = (float2*)(ti + TOKENS);
  int2*   pos       = (int2*)(tg + TOKENS);
  int*    pair_tok  = (int*)(pos + TOKENS);
  float*  pair_gate = (float*)(pair_tok + NPAIRS);
  int*    meta      = (int*)(pair_gate + NPAIRS);
  int*    tile_z    = meta + 64;
  int*    tile_row  = tile_z + 512;
  short*  xb        = (short*)(((uintptr_t)(tile_row + 512) + 255) & ~(uintptr_t)255);
  short*  w1t       = xb + (size_t)TOKENS * D_DIM;
  short*  Yr        = xb;   // alias (valid after k_gemm1 completes)

  k_transpose<<<dim3(F_DIM / 32, D_DIM / 64, NZ), 256, 0, stream>>>(
      ew1, sw1, w1t, D_DIM, F_DIM);
  k_transpose<<<dim3(D_DIM / 32, F_DIM / 64, NZ), 256, 0, stream>>>(
      ew2, sw2, w2t, F_DIM, D_DIM);

  k_router<<<TOKENS / 4, 256, 0, stream>>>(x, router_w, router_b, xb, ti, tg,
                                           pair_tok, pair_gate);
  k_count<<<1, 1024, 0, stream>>>(ti, meta, tile_z, tile_row, out + OUT_ELEMS);
  k_assign<<<TOKENS / 256, 256, 0, stream>>>(ti, tg, meta, pair_tok, pair_gate, pos);

  k_gemm1<<<8 * G1_CAP, 256, 0, stream>>>(
      xb, w1t, eb1, sb1, meta, tile_z, tile_row, pair_tok, pair_gate, Hbuf);
  k_gemm2r<<<8 * G2R_CAP, 256, 0, stream>>>(
      Hbuf, w2t, meta, tile_z, tile_row, Yr);
  k_gemm2s<<<1024, 256, 0, stream>>>(
      Hbuf, w2t, ti, tg, eb2, sb2, Yr, pos, out);
}

// Round 22
// 302.329 us; speedup vs baseline: 1.0423x; 1.0235x over previous
//
#include <hip/hip_runtime.h>
#include <hip/hip_bf16.h>
#include <cstdint>

// Problem constants (B=2,S=4096,D=2048,E=8,SH=2,F=512,K=2)
#define TOKENS   8192
#define D_DIM    2048
#define F_DIM    512
#define NE       8
#define NSH      2
#define NZ       10
#define OUT_ELEMS (TOKENS * D_DIM)

// pair bookkeeping: routed capacity padded to 128-row tiles, then shared pairs
#define RCAP     17408                  // sum ceil(c_e/128)*128 <= 16384+8*127
#define SH_BASE  RCAP
#define NPAIRS   (RCAP + 2 * TOKENS)    // 33792
#define MAX_RT   136                    // max routed 128-row M-tiles
// per-XCD caps (top-2 distinct => count_e <= 8192 => nt_e <= 64)
#define G1_CAP   640                    // 64*8 + 128 shared items (64-col tiles)
#define G2R_CAP  2048                   // 64*32 (64-col tiles)

// fused prep kernel block ranges
#define PREP_T1  5120                   // w1t transpose blocks
#define PREP_T2  5120                   // w2t transpose blocks
#define PREP_RT  2048                   // router blocks
#define PREP_G   (PREP_T1 + PREP_T2 + PREP_RT)

typedef __attribute__((ext_vector_type(8))) short bf16x8;
typedef __attribute__((ext_vector_type(4))) float f32x4;

__device__ __forceinline__ short f2bf(float f) {
  union { float f; uint32_t u; } v; v.f = f;
  uint32_t r = (v.u + 0x7fffu + ((v.u >> 16) & 1u)) >> 16;
  return (short)r;
}
__device__ __forceinline__ float bf2f(short s) {
  union { float f; uint32_t u; } v; v.u = ((uint32_t)(uint16_t)s) << 16; return v.f;
}

__device__ __forceinline__ void gload_lds16(const void* g, void* l) {
  __builtin_amdgcn_global_load_lds(
      (const __attribute__((address_space(1))) unsigned int*)g,
      (__attribute__((address_space(3))) unsigned int*)l,
      16, 0, 0);
}

// ---- fused prep: both weight transposes + router in one flat launch --------
// b in [0,5120): w1t slice; [5120,10240): w2t slice; [10240,12288): router.
__global__ __launch_bounds__(256) void k_prep(
    const float* __restrict__ ew1, const float* __restrict__ sw1,
    short* __restrict__ w1t,
    const float* __restrict__ ew2, const float* __restrict__ sw2,
    short* __restrict__ w2t,
    const float* __restrict__ x, const float* __restrict__ rw,
    const float* __restrict__ rb, short* __restrict__ xb,
    int2* __restrict__ ti, float2* __restrict__ tg,
    int* __restrict__ pair_tok, float* __restrict__ pair_gate) {
  const int b = blockIdx.x;
  __shared__ float tile[64][33];
  if (b < PREP_T1 + PREP_T2) {
    // ---- transpose-convert fp32 (R,C) -> bf16 (C,R), vectorized stores ----
    const float *ein, *sin_; short* outp; int R, C, cx, ry, z;
    if (b < PREP_T1) {
      ein = ew1; sin_ = sw1; outp = w1t; R = D_DIM; C = F_DIM;
      cx = b & 15; ry = (b >> 4) & 31; z = b >> 9;        // 16 x 32 per slice
    } else {
      int b2 = b - PREP_T1;
      ein = ew2; sin_ = sw2; outp = w2t; R = F_DIM; C = D_DIM;
      cx = b2 & 63; ry = (b2 >> 6) & 7; z = b2 >> 9;      // 64 x 8 per slice
    }
    const float* in = (z < NE) ? (ein + (size_t)z * R * C)
                               : (sin_ + (size_t)(z - NE) * R * C);
    short* out = outp + (size_t)z * R * C;
    int c0 = cx * 32, r0 = ry * 64;
    int id = threadIdx.x;
    int lc = id & 31, lr = id >> 5;
    #pragma unroll
    for (int i = 0; i < 8; i++) {
      int row = i * 8 + lr;
      tile[row][lc] = in[(size_t)(r0 + row) * C + c0 + lc];
    }
    __syncthreads();
    short4* out4 = (short4*)out;
    #pragma unroll
    for (int j = 0; j < 2; j++) {
      int s = j * 256 + id;
      int c = s >> 4, q = s & 15;
      short4 o;
      o.x = f2bf(tile[4 * q + 0][c]);
      o.y = f2bf(tile[4 * q + 1][c]);
      o.z = f2bf(tile[4 * q + 2][c]);
      o.w = f2bf(tile[4 * q + 3][c]);
      out4[(((size_t)(c0 + c) * R) + r0) / 4 + q] = o;
    }
  } else {
    // ---- router: wave-per-token, fp32 float4, exact top-2; writes xb ------
    const int br = b - (PREP_T1 + PREP_T2);
    int gid = br * 256 + threadIdx.x;
    if (gid < RCAP) { pair_tok[gid] = 0; pair_gate[gid] = 0.f; }
    int wave = threadIdx.x >> 6;
    int lane = threadIdx.x & 63;
    int t = br * 4 + wave;
    const float4* xr = (const float4*)(x + (size_t)t * D_DIM);
    short4* xbr = (short4*)(xb + (size_t)t * D_DIM);
    const float4* rw4 = (const float4*)rw;
    float acc[NE];
    #pragma unroll
    for (int e = 0; e < NE; e++) acc[e] = 0.f;
    #pragma unroll
    for (int it = 0; it < D_DIM / 4 / 64; it++) {
      int i = it * 64 + lane;
      float4 v = xr[i];
      short4 o;
      o.x = f2bf(v.x); o.y = f2bf(v.y); o.z = f2bf(v.z); o.w = f2bf(v.w);
      xbr[i] = o;
      #pragma unroll
      for (int e = 0; e < NE; e++) {
        float4 w = rw4[e * (D_DIM / 4) + i];
        acc[e] += v.x * w.x + v.y * w.y + v.z * w.z + v.w * w.w;
      }
    }
    #pragma unroll
    for (int e = 0; e < NE; e++) {
      #pragma unroll
      for (int off = 32; off > 0; off >>= 1) acc[e] += __shfl_xor(acc[e], off);
    }
    if (lane == 0) {
      float lg[NE];
      #pragma unroll
      for (int e = 0; e < NE; e++) lg[e] = acc[e] + rb[e];
      int i0 = 0;
      #pragma unroll
      for (int e = 1; e < NE; e++) if (lg[e] > lg[i0]) i0 = e;
      int i1 = (i0 == 0) ? 1 : 0;
      #pragma unroll
      for (int e = 0; e < NE; e++) if (e != i0 && e != i1 && lg[e] > lg[i1]) i1 = e;
      float e1 = __expf(lg[i1] - lg[i0]);
      float inv = 1.f / (1.f + e1);
      ti[t] = make_int2(i0, i1);
      tg[t] = make_float2(inv, e1 * inv);
    }
  }
}

// ------ count + tile table (parallel fill) + aux loss (single block) --------
__global__ __launch_bounds__(1024) void k_count(
    const int2* __restrict__ ti, int* __restrict__ meta,
    int* __restrict__ tile_z, int* __restrict__ tile_row,
    float* __restrict__ out_loss) {
  __shared__ int cnt[NE + 2];
  __shared__ int tb[NE + 1];
  __shared__ int sb[NE];
  if (threadIdx.x < NE + 2) cnt[threadIdx.x] = 0;
  __syncthreads();
  int loc[NE]; int l0 = 0, l1 = 0;
  #pragma unroll
  for (int e = 0; e < NE; e++) loc[e] = 0;
  for (int t = threadIdx.x; t < TOKENS; t += 1024) {
    int2 ii = ti[t];
    loc[ii.x]++; loc[ii.y]++;
    l0 += (ii.x == 0); l1 += (ii.y == 1);
  }
  #pragma unroll
  for (int e = 0; e < NE; e++) if (loc[e]) atomicAdd(&cnt[e], loc[e]);
  if (l0) atomicAdd(&cnt[NE], l0);
  if (l1) atomicAdd(&cnt[NE + 1], l1);
  __syncthreads();
  if (threadIdx.x == 0) {
    int base = 0, nrt = 0;
    #pragma unroll
    for (int e = 0; e < NE; e++) {
      int c = cnt[e];
      meta[e] = c;
      meta[19 + e] = base;
      meta[8 + e] = 0;                       // cursor
      int nt = (c + 127) >> 7;
      meta[40 + e] = nrt;                    // tile-slot base
      meta[48 + e] = nt;                     // tile count
      sb[e] = base; tb[e] = nrt;
      nrt += nt; base += nt * 128;
    }
    tb[NE] = nrt;
    meta[18] = nrt;
    float p0 = (float)cnt[NE] / 16384.0f + 1e-8f;
    float p1 = (float)cnt[NE + 1] / 16384.0f + 1e-8f;
    float rest = 6.0f * (1e-8f * logf(1e-8f));
    out_loss[0] = -(p0 * logf(p0) + p1 * logf(p1) + rest);
  }
  __syncthreads();
  int s = threadIdx.x;
  if (s < tb[NE]) {
    int e = 0;
    #pragma unroll
    for (int k = 1; k < NE; k++) if (s >= tb[k]) e = k;
    tile_z[s] = e;
    tile_row[s] = sb[e] + (s - tb[e]) * 128;
  }
  if (s < 128) {
    tile_z[MAX_RT + s] = NE + (s >> 6);
    tile_row[MAX_RT + s] = SH_BASE + (s >> 6) * TOKENS + (s & 63) * 128;
  }
}

// ---------------- assignment: ballot-scan within wave + inverse map ---------
__global__ __launch_bounds__(256) void k_assign(
    const int2* __restrict__ ti, const float2* __restrict__ tg,
    int* __restrict__ meta, int* __restrict__ pair_tok, float* __restrict__ pair_gate,
    int2* __restrict__ pos) {
  int t = blockIdx.x * 256 + threadIdx.x;
  int lane = threadIdx.x & 63;
  int2 ii = ti[t];
  float2 gg = tg[t];
  int2 mypos;
  unsigned long long below = (1ull << lane) - 1ull;
  #pragma unroll
  for (int e = 0; e < NE; e++) {
    unsigned long long m0 = __ballot(ii.x == e);
    unsigned long long m1 = __ballot(ii.y == e);
    unsigned c = __popcll(m0) + __popcll(m1);
    unsigned base = 0;
    if (lane == 0 && c) base = atomicAdd((unsigned*)&meta[8 + e], c);
    base = __shfl((int)base, 0);
    int seg = meta[19 + e];
    if (ii.x == e) {
      int p = seg + base + __popcll(m0 & below);
      pair_tok[p] = t; pair_gate[p] = gg.x; mypos.x = p;
    }
    if (ii.y == e) {
      int p = seg + base + __popcll(m0) + __popcll(m1 & below);
      pair_tok[p] = t; pair_gate[p] = gg.y; mypos.y = p;
    }
  }
  pos[t] = mypos;
  pair_tok[SH_BASE + t] = t;            pair_gate[SH_BASE + t] = 1.f;
  pair_tok[SH_BASE + TOKENS + t] = t;   pair_gate[SH_BASE + TOKENS + t] = 1.f;
}

// ============================================================================
// GEMM cores: r17 skeleton (body order + compile-time-buffer unroll), two
// geometries (r19/r21 measured best = ~309us):
//  - 128x64 tiles (gemm1/gemm2r): A 128rows + B 64rows, dbuf LDS 48KB ->
//    3 blocks/CU. 6 gloads/thread/tile -> vmcnt(6) ledger ({t:6,t+1:6}).
//  - 128x128 (gemm2s): 64KB LDS, vmcnt(8), 32 MFMA/tile (perfect fill:
//    1024 items / 512 slots; r20 proved 128x64 here REGRESSES).
// XOR &7 swizzle on 128B rows (0 conflicts), XCD expert pinning.
// ============================================================================

#define GBODY_N2(T_, BUF_, NTV, STAGE_MACRO)                              \
    if ((T_) + 1 < (NTV)) asm volatile("s_waitcnt vmcnt(6)" ::: "memory");\
    else                  asm volatile("s_waitcnt vmcnt(0)" ::: "memory");\
    __builtin_amdgcn_s_barrier();                                         \
    asm volatile("" ::: "memory");                                        \
    {                                                                     \
      bf16x8 af0[4], bf0[2], af1[4], bf1[2];                              \
      _Pragma("unroll") for (int m = 0; m < 4; m++) {                     \
        af0[m] = *(const bf16x8*)&As[BUF_][rowAo[m] + slt0];              \
        af1[m] = *(const bf16x8*)&As[BUF_][rowAo[m] + slt1];              \
      }                                                                   \
      _Pragma("unroll") for (int n = 0; n < 2; n++) {                     \
        bf0[n] = *(const bf16x8*)&Bs[BUF_][rowBo[n] + slt0];              \
        bf1[n] = *(const bf16x8*)&Bs[BUF_][rowBo[n] + slt1];              \
      }                                                                   \
      asm volatile("s_waitcnt lgkmcnt(0)" ::: "memory");                  \
      __builtin_amdgcn_sched_barrier(0);                                  \
      __builtin_amdgcn_s_barrier();                                       \
      asm volatile("" ::: "memory");                                      \
      if ((T_) + 2 < (NTV)) STAGE_MACRO(BUF_, (T_) + 2);                  \
      __builtin_amdgcn_s_setprio(1);                                      \
      _Pragma("unroll") for (int m = 0; m < 4; m++)                       \
        _Pragma("unroll") for (int n = 0; n < 2; n++)                     \
          acc[m][n] = __builtin_amdgcn_mfma_f32_16x16x32_bf16(            \
              af0[m], bf0[n], acc[m][n], 0, 0, 0);                        \
      _Pragma("unroll") for (int m = 0; m < 4; m++)                       \
        _Pragma("unroll") for (int n = 0; n < 2; n++)                     \
          acc[m][n] = __builtin_amdgcn_mfma_f32_16x16x32_bf16(            \
              af1[m], bf1[n], acc[m][n], 0, 0, 0);                        \
      __builtin_amdgcn_s_setprio(0);                                      \
    }

#define GBODY_N4(T_, BUF_, NTV, STAGE_MACRO)                              \
    if ((T_) + 1 < (NTV)) asm volatile("s_waitcnt vmcnt(8)" ::: "memory");\
    else                  asm volatile("s_waitcnt vmcnt(0)" ::: "memory");\
    __builtin_amdgcn_s_barrier();                                         \
    asm volatile("" ::: "memory");                                        \
    {                                                                     \
      bf16x8 af0[4], bf0[4], af1[4], bf1[4];                              \
      _Pragma("unroll") for (int m = 0; m < 4; m++) {                     \
        af0[m] = *(const bf16x8*)&As[BUF_][rowAo[m] + slt0];              \
        bf0[m] = *(const bf16x8*)&Bs[BUF_][rowBo[m] + slt0];              \
        af1[m] = *(const bf16x8*)&As[BUF_][rowAo[m] + slt1];              \
        bf1[m] = *(const bf16x8*)&Bs[BUF_][rowBo[m] + slt1];              \
      }                                                                   \
      asm volatile("s_waitcnt lgkmcnt(0)" ::: "memory");                  \
      __builtin_amdgcn_sched_barrier(0);                                  \
      __builtin_amdgcn_s_barrier();                                       \
      asm volatile("" ::: "memory");                                      \
      if ((T_) + 2 < (NTV)) STAGE_MACRO(BUF_, (T_) + 2);                  \
      __builtin_amdgcn_s_setprio(1);                                      \
      _Pragma("unroll") for (int m = 0; m < 4; m++)                       \
        _Pragma("unroll") for (int n = 0; n < 4; n++)                     \
          acc[m][n] = __builtin_amdgcn_mfma_f32_16x16x32_bf16(            \
              af0[m], bf0[n], acc[m][n], 0, 0, 0);                        \
      _Pragma("unroll") for (int m = 0; m < 4; m++)                       \
        _Pragma("unroll") for (int n = 0; n < 4; n++)                     \
          acc[m][n] = __builtin_amdgcn_mfma_f32_16x16x32_bf16(            \
              af1[m], bf1[n], acc[m][n], 0, 0, 0);                        \
      __builtin_amdgcn_s_setprio(0);                                      \
    }

// ---------------- GEMM1: H[p] = gelu(x[tok(p)]@W1[z]+b1)*gate ---------------
// 128x64 tiles, F=512 -> 8 bn. grid 8*G1_CAP, XCD-pinned. 3 blocks/CU.
__global__ __launch_bounds__(256, 3) void k_gemm1(
    const short* __restrict__ xb, const short* __restrict__ w1t,
    const float* __restrict__ eb1, const float* __restrict__ sb1,
    const int* __restrict__ meta, const int* __restrict__ tile_z,
    const int* __restrict__ tile_row, const int* __restrict__ pair_tok,
    const float* __restrict__ pair_gate, short* __restrict__ H) {
  const int l = blockIdx.x;
  const int xcd = l & 7;
  const int i = l >> 3;
  const int ntx = meta[48 + xcd];
  int slot, bn;
  if (i < ntx * 8) {
    slot = meta[40 + xcd] + (i >> 3); bn = i & 7;
  } else {
    int j = i - ntx * 8;
    if (j >= 128) return;
    int js = xcd * 128 + j;                // 1024 shared items, 128 per XCD
    slot = MAX_RT + (js >> 3); bn = js & 7;
  }
  const int z = tile_z[slot];
  const int row0 = tile_row[slot];
  __shared__ __align__(16) short As[2][8192];
  __shared__ __align__(16) short Bs[2][4096];
  const int tid = threadIdx.x;
  const int lane = tid & 63;
  const int wv = tid >> 6;
  const int wm = wv >> 1, wn = wv & 1;

  const short* asrc[4]; const short* bsrc[2];
  {
    const short* wb = w1t + (size_t)z * F_DIM * D_DIM;
    int shtok = 0;
    if (slot >= MAX_RT) {
      shtok = row0 - SH_BASE;
      if (shtok >= TOKENS) shtok -= TOKENS;
    }
    #pragma unroll
    for (int i2 = 0; i2 < 4; i2++) {
      int id = i2 * 256 + tid;
      int row = id >> 3, c = id & 7;
      int kc = ((c ^ (row & 7)) << 3);
      int arow = (slot < MAX_RT) ? pair_tok[row0 + row] : (shtok + row);
      asrc[i2] = xb + (size_t)arow * D_DIM + kc;
    }
    #pragma unroll
    for (int i2 = 0; i2 < 2; i2++) {
      int id = i2 * 256 + tid;
      int row = id >> 3, c = id & 7;     // row 0..63
      int kc = ((c ^ (row & 7)) << 3);
      bsrc[i2] = wb + (size_t)(bn * 64 + row) * D_DIM + kc;
    }
  }

  const int slt0 = (((lane >> 4)) ^ (lane & 7)) << 3;
  const int slt1 = ((4 + (lane >> 4)) ^ (lane & 7)) << 3;
  int rowAo[4], rowBo[2];
  #pragma unroll
  for (int m = 0; m < 4; m++)
    rowAo[m] = (wm * 64 + m * 16 + (lane & 15)) * 64;
  #pragma unroll
  for (int n = 0; n < 2; n++)
    rowBo[n] = (wn * 32 + n * 16 + (lane & 15)) * 64;

  f32x4 acc[4][2];
  #pragma unroll
  for (int m = 0; m < 4; m++)
    #pragma unroll
    for (int n = 0; n < 2; n++) acc[m][n] = (f32x4)(0.f);

  #define STAGE1(BUF, TT) do {                                            \
      int k0_ = (TT) * 64;                                                \
      _Pragma("unroll") for (int i2 = 0; i2 < 4; i2++)                    \
        gload_lds16(asrc[i2] + k0_, &As[BUF][(i2 * 256 + tid) * 8]);      \
      _Pragma("unroll") for (int i2 = 0; i2 < 2; i2++)                    \
        gload_lds16(bsrc[i2] + k0_, &Bs[BUF][(i2 * 256 + tid) * 8]);      \
    } while (0)

  STAGE1(0, 0);
  STAGE1(1, 1);

  const int NT = D_DIM / 64;   // 32 (even)
  for (int t = 0; t < NT; t += 2) {
    GBODY_N2(t,     0, NT, STAGE1);
    GBODY_N2(t + 1, 1, NT, STAGE1);
  }
  #undef STAGE1

  const float* b1 = (z < NE) ? (eb1 + z * F_DIM) : (sb1 + (size_t)(z - NE) * F_DIM);
  #pragma unroll
  for (int m = 0; m < 4; m++) {
    #pragma unroll
    for (int r = 0; r < 4; r++) {
      int row = wm * 64 + m * 16 + (lane >> 4) * 4 + r;
      float g = pair_gate[row0 + row];
      #pragma unroll
      for (int n = 0; n < 2; n++) {
        int col = bn * 64 + wn * 32 + n * 16 + (lane & 15);
        float c = acc[m][n][r] + b1[col];
        float h = 0.5f * c * (1.0f + erff(c * 0.70710678118654752440f));
        H[(size_t)(row0 + row) * F_DIM + col] = f2bf(h * g);
      }
    }
  }
}

// ---------------- GEMM2 routed: Yr[p] = H[p] @ W2t[z]  (K=512) --------------
// 128x64 tiles, D=2048 -> 32 bn. grid 8*G2R_CAP. 3 blocks/CU.
__global__ __launch_bounds__(256, 3) void k_gemm2r(
    const short* __restrict__ Hb, const short* __restrict__ w2t,
    const int* __restrict__ meta, const int* __restrict__ tile_z,
    const int* __restrict__ tile_row, short* __restrict__ Yr) {
  const int l = blockIdx.x;
  const int xcd = l & 7;
  const int i = l >> 3;
  const int ntx = meta[48 + xcd];
  if (i >= ntx * 32) return;
  const int slot = meta[40 + xcd] + (i >> 5);
  const int bn = i & 31;
  const int z = tile_z[slot];
  const int row0 = tile_row[slot];
  __shared__ __align__(16) short As[2][8192];
  __shared__ __align__(16) short Bs[2][4096];
  const int tid = threadIdx.x;
  const int lane = tid & 63;
  const int wv = tid >> 6;
  const int wm = wv >> 1, wn = wv & 1;

  const short* asrc[4]; const short* bsrc[2];
  {
    const short* Bb = w2t + (size_t)z * D_DIM * F_DIM;
    #pragma unroll
    for (int i2 = 0; i2 < 4; i2++) {
      int id = i2 * 256 + tid;
      int row = id >> 3, c = id & 7;
      int kc = ((c ^ (row & 7)) << 3);
      asrc[i2] = Hb + (size_t)(row0 + row) * F_DIM + kc;
    }
    #pragma unroll
    for (int i2 = 0; i2 < 2; i2++) {
      int id = i2 * 256 + tid;
      int row = id >> 3, c = id & 7;
      int kc = ((c ^ (row & 7)) << 3);
      bsrc[i2] = Bb + (size_t)(bn * 64 + row) * F_DIM + kc;
    }
  }

  const int slt0 = (((lane >> 4)) ^ (lane & 7)) << 3;
  const int slt1 = ((4 + (lane >> 4)) ^ (lane & 7)) << 3;
  int rowAo[4], rowBo[2];
  #pragma unroll
  for (int m = 0; m < 4; m++)
    rowAo[m] = (wm * 64 + m * 16 + (lane & 15)) * 64;
  #pragma unroll
  for (int n = 0; n < 2; n++)
    rowBo[n] = (wn * 32 + n * 16 + (lane & 15)) * 64;

  f32x4 acc[4][2];
  #pragma unroll
  for (int m = 0; m < 4; m++)
    #pragma unroll
    for (int n = 0; n < 2; n++) acc[m][n] = (f32x4)(0.f);

  #define STAGE2R(BUF, TT) do {                                           \
      int k0_ = (TT) * 64;                                                \
      _Pragma("unroll") for (int i2 = 0; i2 < 4; i2++)                    \
        gload_lds16(asrc[i2] + k0_, &As[BUF][(i2 * 256 + tid) * 8]);      \
      _Pragma("unroll") for (int i2 = 0; i2 < 2; i2++)                    \
        gload_lds16(bsrc[i2] + k0_, &Bs[BUF][(i2 * 256 + tid) * 8]);      \
    } while (0)

  STAGE2R(0, 0);
  STAGE2R(1, 1);

  const int NT = F_DIM / 64;   // 8 (even)
  for (int t = 0; t < NT; t += 2) {
    GBODY_N2(t,     0, NT, STAGE2R);
    GBODY_N2(t + 1, 1, NT, STAGE2R);
  }
  #undef STAGE2R

  #pragma unroll
  for (int m = 0; m < 4; m++) {
    #pragma unroll
    for (int r = 0; r < 4; r++) {
      int row = wm * 64 + m * 16 + (lane >> 4) * 4 + r;
      #pragma unroll
      for (int n = 0; n < 2; n++) {
        int col = bn * 64 + wn * 32 + n * 16 + (lane & 15);
        Yr[(size_t)(row0 + row) * D_DIM + col] = f2bf(acc[m][n][r]);
      }
    }
  }
}

// -------- GEMM2 shared (K=1024) + fused combine: out = shared + biases + Yr -
// 128x128 tiles (r19 config; perfect fill: 1024 items / 512 slots).
__global__ __launch_bounds__(256, 2) void k_gemm2s(
    const short* __restrict__ Hb, const short* __restrict__ w2t,
    const int2* __restrict__ ti, const float2* __restrict__ tg,
    const float* __restrict__ eb2, const float* __restrict__ sb2,
    const short* __restrict__ Yr, const int2* __restrict__ pos,
    float* __restrict__ out) {
  const int l = blockIdx.x;
  const int js = (l & 7) * 128 + (l >> 3);
  const int t0 = (js >> 4) * 128;
  const int bn = js & 15;
  __shared__ __align__(16) short As[2][8192];
  __shared__ __align__(16) short Bs[2][8192];
  const int tid = threadIdx.x;
  const int lane = tid & 63;
  const int wv = tid >> 6;
  const int wm = wv >> 1, wn = wv & 1;

  size_t aoff[4], boff[4];
  #pragma unroll
  for (int i2 = 0; i2 < 4; i2++) {
    int id = i2 * 256 + tid;
    int row = id >> 3, c = id & 7;
    int kc = ((c ^ (row & 7)) << 3);
    aoff[i2] = (size_t)row * F_DIM + kc;
    boff[i2] = (size_t)(bn * 128 + row) * F_DIM + kc;
  }
  const short* Abase0 = Hb + (size_t)(SH_BASE + t0) * F_DIM;
  const short* Bbase0 = w2t + (size_t)NE * D_DIM * F_DIM;

  const int slt0 = (((lane >> 4)) ^ (lane & 7)) << 3;
  const int slt1 = ((4 + (lane >> 4)) ^ (lane & 7)) << 3;
  int rowAo[4], rowBo[4];
  #pragma unroll
  for (int m = 0; m < 4; m++) {
    rowAo[m] = (wm * 64 + m * 16 + (lane & 15)) * 64;
    rowBo[m] = (wn * 64 + m * 16 + (lane & 15)) * 64;
  }

  f32x4 acc[4][4];
  #pragma unroll
  for (int m = 0; m < 4; m++)
    #pragma unroll
    for (int n = 0; n < 4; n++) acc[m][n] = (f32x4)(0.f);

  #define STAGE2S(BUF, TT) do {                                           \
      int kcol_ = ((TT) * 64) & (F_DIM - 1);                              \
      const short* Ab_ = Abase0;                                          \
      const short* Bb_ = Bbase0;                                          \
      if ((TT) >= 8) {                                                    \
        Ab_ += (size_t)TOKENS * F_DIM;                                    \
        Bb_ += (size_t)D_DIM * F_DIM;                                     \
      }                                                                   \
      _Pragma("unroll") for (int i2 = 0; i2 < 4; i2++) {                  \
        int id_ = i2 * 256 + tid;                                         \
        gload_lds16(Ab_ + aoff[i2] + kcol_, &As[BUF][id_ * 8]);           \
        gload_lds16(Bb_ + boff[i2] + kcol_, &Bs[BUF][id_ * 8]);           \
      }                                                                   \
    } while (0)

  STAGE2S(0, 0);
  STAGE2S(1, 1);

  const int NT = 16;
  for (int t = 0; t < NT; t += 2) {
    GBODY_N4(t,     0, NT, STAGE2S);
    GBODY_N4(t + 1, 1, NT, STAGE2S);
  }
  #undef STAGE2S

  #pragma unroll
  for (int m = 0; m < 4; m++) {
    #pragma unroll
    for (int r = 0; r < 4; r++) {
      int row = t0 + wm * 64 + m * 16 + (lane >> 4) * 4 + r;
      int2 ii = ti[row]; float2 gg = tg[row];
      int2 p = pos[row];
      #pragma unroll
      for (int n = 0; n < 4; n++) {
        int col = bn * 128 + wn * 64 + n * 16 + (lane & 15);
        float v = acc[m][n][r]
                + gg.x * eb2[(size_t)ii.x * D_DIM + col]
                + gg.y * eb2[(size_t)ii.y * D_DIM + col]
                + sb2[col] + sb2[D_DIM + col]
                + bf2f(Yr[(size_t)p.x * D_DIM + col])
                + bf2f(Yr[(size_t)p.y * D_DIM + col]);
        out[(size_t)row * D_DIM + col] = v;
      }
    }
  }
}

// ---------------------------------------------------------------------------
extern "C" void kernel_launch(void* const* d_in, const int* in_sizes, int n_in,
                              void* d_out, int out_size, void* d_ws, size_t ws_size,
                              hipStream_t stream) {
  (void)in_sizes; (void)n_in; (void)out_size; (void)ws_size;
  const float* x        = (const float*)d_in[0];
  const float* router_w = (const float*)d_in[1];
  const float* router_b = (const float*)d_in[2];
  const float* ew1      = (const float*)d_in[3];
  const float* eb1      = (const float*)d_in[4];
  const float* ew2      = (const float*)d_in[5];
  const float* eb2      = (const float*)d_in[6];
  const float* sw1      = (const float*)d_in[7];
  const float* sb1      = (const float*)d_in[8];
  const float* sw2      = (const float*)d_in[9];
  const float* sb2      = (const float*)d_in[10];
  float* out = (float*)d_out;

  // workspace layout (Yr aliases xb+w1t+overhang; dead after k_gemm1):
  //   w2t 20.97MB | Hbuf 34.6MB | small ~0.6MB | xb 33.55MB | w1t 20.97MB |
  //   Yr-overhang ~17MB  => total ~128MB
  char* ws = (char*)d_ws;
  short*  w2t       = (short*)ws;
  short*  Hbuf      = w2t + (size_t)NZ * D_DIM * F_DIM;
  int2*   ti        = (int2*)(Hbuf + (size_t)NPAIRS * F_DIM);
  float2* tg        = (float2*)(ti + TOKENS);
  int2*   pos       = (int2*)(tg + TOKENS);
  int*    pair_tok  = (int*)(pos + TOKENS);
  float*  pair_gate = (float*)(pair_tok + NPAIRS);
  int*    meta      = (int*)(pair_gate + NPAIRS);
  int*    tile_z    = meta + 64;
  int*    tile_row  = tile_z + 512;
  short*  xb        = (short*)(((uintptr_t)(tile_row + 512) + 255) & ~(uintptr_t)255);
  short*  w1t       = xb + (size_t)TOKENS * D_DIM;
  short*  Yr        = xb;   // alias (valid after k_gemm1 completes)

  k_prep<<<PREP_G, 256, 0, stream>>>(
      ew1, sw1, w1t, ew2, sw2, w2t,
      x, router_w, router_b, xb, ti, tg, pair_tok, pair_gate);
  k_count<<<1, 1024, 0, stream>>>(ti, meta, tile_z, tile_row, out + OUT_ELEMS);
  k_assign<<<TOKENS / 256, 256, 0, stream>>>(ti, tg, meta, pair_tok, pair_gate, pos);

  k_gemm1<<<8 * G1_CAP, 256, 0, stream>>>(
      xb, w1t, eb1, sb1, meta, tile_z, tile_row, pair_tok, pair_gate, Hbuf);
  k_gemm2r<<<8 * G2R_CAP, 256, 0, stream>>>(
      Hbuf, w2t, meta, tile_z, tile_row, Yr);
  k_gemm2s<<<1024, 256, 0, stream>>>(
      Hbuf, w2t, ti, tg, eb2, sb2, Yr, pos, out);
}

// Round 23
// 298.050 us; speedup vs baseline: 1.0573x; 1.0144x over previous
//
#include <hip/hip_runtime.h>
#include <hip/hip_bf16.h>
#include <cstdint>

// Problem constants (B=2,S=4096,D=2048,E=8,SH=2,F=512,K=2)
#define TOKENS   8192
#define D_DIM    2048
#define F_DIM    512
#define NE       8
#define NSH      2
#define NZ       10
#define OUT_ELEMS (TOKENS * D_DIM)

// pair bookkeeping: routed capacity padded to 128-row tiles, then shared pairs
#define RCAP     17408                  // sum ceil(c_e/128)*128 <= 16384+8*127
#define SH_BASE  RCAP
#define NPAIRS   (RCAP + 2 * TOKENS)    // 33792
#define MAX_RT   136                    // max routed 128-row M-tiles
// per-XCD caps (top-2 distinct => count_e <= 8192 => nt_e <= 64)
#define G1_CAP   640                    // 64*8 + 128 shared items (64-col tiles)
#define G2R_CAP  2048                   // 64*32 (64-col tiles)

// fused prep kernel block ranges
#define PREP_T1  5120                   // w1t transpose blocks
#define PREP_T2  5120                   // w2t transpose blocks
#define PREP_RT  2048                   // router blocks
#define PREP_G   (PREP_T1 + PREP_T2 + PREP_RT)

typedef __attribute__((ext_vector_type(8))) short bf16x8;
typedef __attribute__((ext_vector_type(4))) float f32x4;

__device__ __forceinline__ short f2bf(float f) {
  union { float f; uint32_t u; } v; v.f = f;
  uint32_t r = (v.u + 0x7fffu + ((v.u >> 16) & 1u)) >> 16;
  return (short)r;
}
__device__ __forceinline__ float bf2f(short s) {
  union { float f; uint32_t u; } v; v.u = ((uint32_t)(uint16_t)s) << 16; return v.f;
}

// Abramowitz-Stegun 7.1.26 erf: max abs error 1.5e-7 (invisible vs bf16 store)
__device__ __forceinline__ float erf_fast(float x) {
  float ax = fabsf(x);
  float t = __frcp_rn(1.f + 0.3275911f * ax);
  float p = t * (0.254829592f + t * (-0.284496736f + t * (1.421413741f +
            t * (-1.453152027f + t * 1.061405429f))));
  float r = 1.f - p * __expf(-ax * ax);
  return copysignf(r, x);
}

__device__ __forceinline__ void gload_lds16(const void* g, void* l) {
  __builtin_amdgcn_global_load_lds(
      (const __attribute__((address_space(1))) unsigned int*)g,
      (__attribute__((address_space(3))) unsigned int*)l,
      16, 0, 0);
}

// ---- fused prep: both weight transposes + router in one flat launch --------
// b in [0,5120): w1t slice; [5120,10240): w2t slice; [10240,12288): router.
__global__ __launch_bounds__(256) void k_prep(
    const float* __restrict__ ew1, const float* __restrict__ sw1,
    short* __restrict__ w1t,
    const float* __restrict__ ew2, const float* __restrict__ sw2,
    short* __restrict__ w2t,
    const float* __restrict__ x, const float* __restrict__ rw,
    const float* __restrict__ rb, short* __restrict__ xb,
    int2* __restrict__ ti, float2* __restrict__ tg,
    int* __restrict__ pair_tok, float* __restrict__ pair_gate) {
  const int b = blockIdx.x;
  __shared__ float tile[64][33];
  if (b < PREP_T1 + PREP_T2) {
    const float *ein, *sin_; short* outp; int R, C, cx, ry, z;
    if (b < PREP_T1) {
      ein = ew1; sin_ = sw1; outp = w1t; R = D_DIM; C = F_DIM;
      cx = b & 15; ry = (b >> 4) & 31; z = b >> 9;        // 16 x 32 per slice
    } else {
      int b2 = b - PREP_T1;
      ein = ew2; sin_ = sw2; outp = w2t; R = F_DIM; C = D_DIM;
      cx = b2 & 63; ry = (b2 >> 6) & 7; z = b2 >> 9;      // 64 x 8 per slice
    }
    const float* in = (z < NE) ? (ein + (size_t)z * R * C)
                               : (sin_ + (size_t)(z - NE) * R * C);
    short* out = outp + (size_t)z * R * C;
    int c0 = cx * 32, r0 = ry * 64;
    int id = threadIdx.x;
    int lc = id & 31, lr = id >> 5;
    #pragma unroll
    for (int i = 0; i < 8; i++) {
      int row = i * 8 + lr;
      tile[row][lc] = in[(size_t)(r0 + row) * C + c0 + lc];
    }
    __syncthreads();
    short4* out4 = (short4*)out;
    #pragma unroll
    for (int j = 0; j < 2; j++) {
      int s = j * 256 + id;
      int c = s >> 4, q = s & 15;
      short4 o;
      o.x = f2bf(tile[4 * q + 0][c]);
      o.y = f2bf(tile[4 * q + 1][c]);
      o.z = f2bf(tile[4 * q + 2][c]);
      o.w = f2bf(tile[4 * q + 3][c]);
      out4[(((size_t)(c0 + c) * R) + r0) / 4 + q] = o;
    }
  } else {
    const int br = b - (PREP_T1 + PREP_T2);
    int gid = br * 256 + threadIdx.x;
    if (gid < RCAP) { pair_tok[gid] = 0; pair_gate[gid] = 0.f; }
    int wave = threadIdx.x >> 6;
    int lane = threadIdx.x & 63;
    int t = br * 4 + wave;
    const float4* xr = (const float4*)(x + (size_t)t * D_DIM);
    short4* xbr = (short4*)(xb + (size_t)t * D_DIM);
    const float4* rw4 = (const float4*)rw;
    float acc[NE];
    #pragma unroll
    for (int e = 0; e < NE; e++) acc[e] = 0.f;
    #pragma unroll
    for (int it = 0; it < D_DIM / 4 / 64; it++) {
      int i = it * 64 + lane;
      float4 v = xr[i];
      short4 o;
      o.x = f2bf(v.x); o.y = f2bf(v.y); o.z = f2bf(v.z); o.w = f2bf(v.w);
      xbr[i] = o;
      #pragma unroll
      for (int e = 0; e < NE; e++) {
        float4 w = rw4[e * (D_DIM / 4) + i];
        acc[e] += v.x * w.x + v.y * w.y + v.z * w.z + v.w * w.w;
      }
    }
    #pragma unroll
    for (int e = 0; e < NE; e++) {
      #pragma unroll
      for (int off = 32; off > 0; off >>= 1) acc[e] += __shfl_xor(acc[e], off);
    }
    if (lane == 0) {
      float lg[NE];
      #pragma unroll
      for (int e = 0; e < NE; e++) lg[e] = acc[e] + rb[e];
      int i0 = 0;
      #pragma unroll
      for (int e = 1; e < NE; e++) if (lg[e] > lg[i0]) i0 = e;
      int i1 = (i0 == 0) ? 1 : 0;
      #pragma unroll
      for (int e = 0; e < NE; e++) if (e != i0 && e != i1 && lg[e] > lg[i1]) i1 = e;
      float e1 = __expf(lg[i1] - lg[i0]);
      float inv = 1.f / (1.f + e1);
      ti[t] = make_int2(i0, i1);
      tg[t] = make_float2(inv, e1 * inv);
    }
  }
}

// ------ count + tile table (parallel fill) + aux loss (single block) --------
__global__ __launch_bounds__(1024) void k_count(
    const int2* __restrict__ ti, int* __restrict__ meta,
    int* __restrict__ tile_z, int* __restrict__ tile_row,
    float* __restrict__ out_loss) {
  __shared__ int cnt[NE + 2];
  __shared__ int tb[NE + 1];
  __shared__ int sb[NE];
  if (threadIdx.x < NE + 2) cnt[threadIdx.x] = 0;
  __syncthreads();
  int loc[NE]; int l0 = 0, l1 = 0;
  #pragma unroll
  for (int e = 0; e < NE; e++) loc[e] = 0;
  for (int t = threadIdx.x; t < TOKENS; t += 1024) {
    int2 ii = ti[t];
    loc[ii.x]++; loc[ii.y]++;
    l0 += (ii.x == 0); l1 += (ii.y == 1);
  }
  #pragma unroll
  for (int e = 0; e < NE; e++) if (loc[e]) atomicAdd(&cnt[e], loc[e]);
  if (l0) atomicAdd(&cnt[NE], l0);
  if (l1) atomicAdd(&cnt[NE + 1], l1);
  __syncthreads();
  if (threadIdx.x == 0) {
    int base = 0, nrt = 0;
    #pragma unroll
    for (int e = 0; e < NE; e++) {
      int c = cnt[e];
      meta[e] = c;
      meta[19 + e] = base;
      meta[8 + e] = 0;                       // cursor
      int nt = (c + 127) >> 7;
      meta[40 + e] = nrt;                    // tile-slot base
      meta[48 + e] = nt;                     // tile count
      sb[e] = base; tb[e] = nrt;
      nrt += nt; base += nt * 128;
    }
    tb[NE] = nrt;
    meta[18] = nrt;
    float p0 = (float)cnt[NE] / 16384.0f + 1e-8f;
    float p1 = (float)cnt[NE + 1] / 16384.0f + 1e-8f;
    float rest = 6.0f * (1e-8f * logf(1e-8f));
    out_loss[0] = -(p0 * logf(p0) + p1 * logf(p1) + rest);
  }
  __syncthreads();
  int s = threadIdx.x;
  if (s < tb[NE]) {
    int e = 0;
    #pragma unroll
    for (int k = 1; k < NE; k++) if (s >= tb[k]) e = k;
    tile_z[s] = e;
    tile_row[s] = sb[e] + (s - tb[e]) * 128;
  }
  if (s < 128) {
    tile_z[MAX_RT + s] = NE + (s >> 6);
    tile_row[MAX_RT + s] = SH_BASE + (s >> 6) * TOKENS + (s & 63) * 128;
  }
}

// ---------------- assignment: ballot-scan within wave + inverse map ---------
__global__ __launch_bounds__(256) void k_assign(
    const int2* __restrict__ ti, const float2* __restrict__ tg,
    int* __restrict__ meta, int* __restrict__ pair_tok, float* __restrict__ pair_gate,
    int2* __restrict__ pos) {
  int t = blockIdx.x * 256 + threadIdx.x;
  int lane = threadIdx.x & 63;
  int2 ii = ti[t];
  float2 gg = tg[t];
  int2 mypos;
  unsigned long long below = (1ull << lane) - 1ull;
  #pragma unroll
  for (int e = 0; e < NE; e++) {
    unsigned long long m0 = __ballot(ii.x == e);
    unsigned long long m1 = __ballot(ii.y == e);
    unsigned c = __popcll(m0) + __popcll(m1);
    unsigned base = 0;
    if (lane == 0 && c) base = atomicAdd((unsigned*)&meta[8 + e], c);
    base = __shfl((int)base, 0);
    int seg = meta[19 + e];
    if (ii.x == e) {
      int p = seg + base + __popcll(m0 & below);
      pair_tok[p] = t; pair_gate[p] = gg.x; mypos.x = p;
    }
    if (ii.y == e) {
      int p = seg + base + __popcll(m0) + __popcll(m1 & below);
      pair_tok[p] = t; pair_gate[p] = gg.y; mypos.y = p;
    }
  }
  pos[t] = mypos;
  pair_tok[SH_BASE + t] = t;            pair_gate[SH_BASE + t] = 1.f;
  pair_tok[SH_BASE + TOKENS + t] = t;   pair_gate[SH_BASE + TOKENS + t] = 1.f;
}

// ============================================================================
// GEMM cores: r17 skeleton (body order + compile-time-buffer unroll), two
// geometries (r19/r21/r22 measured best):
//  - 128x64 tiles (gemm1/gemm2r): A 128rows + B 64rows, dbuf LDS 48KB ->
//    3 blocks/CU. 6 gloads/thread/tile -> vmcnt(6) ledger ({t:6,t+1:6}).
//  - 128x128 (gemm2s): 64KB LDS, vmcnt(8), 32 MFMA/tile (perfect fill).
// XOR &7 swizzle on 128B rows (0 conflicts), XCD expert pinning.
// ============================================================================

#define GBODY_N2(T_, BUF_, NTV, STAGE_MACRO)                              \
    if ((T_) + 1 < (NTV)) asm volatile("s_waitcnt vmcnt(6)" ::: "memory");\
    else                  asm volatile("s_waitcnt vmcnt(0)" ::: "memory");\
    __builtin_amdgcn_s_barrier();                                         \
    asm volatile("" ::: "memory");                                        \
    {                                                                     \
      bf16x8 af0[4], bf0[2], af1[4], bf1[2];                              \
      _Pragma("unroll") for (int m = 0; m < 4; m++) {                     \
        af0[m] = *(const bf16x8*)&As[BUF_][rowAo[m] + slt0];              \
        af1[m] = *(const bf16x8*)&As[BUF_][rowAo[m] + slt1];              \
      }                                                                   \
      _Pragma("unroll") for (int n = 0; n < 2; n++) {                     \
        bf0[n] = *(const bf16x8*)&Bs[BUF_][rowBo[n] + slt0];              \
        bf1[n] = *(const bf16x8*)&Bs[BUF_][rowBo[n] + slt1];              \
      }                                                                   \
      asm volatile("s_waitcnt lgkmcnt(0)" ::: "memory");                  \
      __builtin_amdgcn_sched_barrier(0);                                  \
      __builtin_amdgcn_s_barrier();                                       \
      asm volatile("" ::: "memory");                                      \
      if ((T_) + 2 < (NTV)) STAGE_MACRO(BUF_, (T_) + 2);                  \
      __builtin_amdgcn_s_setprio(1);                                      \
      _Pragma("unroll") for (int m = 0; m < 4; m++)                       \
        _Pragma("unroll") for (int n = 0; n < 2; n++)                     \
          acc[m][n] = __builtin_amdgcn_mfma_f32_16x16x32_bf16(            \
              af0[m], bf0[n], acc[m][n], 0, 0, 0);                        \
      _Pragma("unroll") for (int m = 0; m < 4; m++)                       \
        _Pragma("unroll") for (int n = 0; n < 2; n++)                     \
          acc[m][n] = __builtin_amdgcn_mfma_f32_16x16x32_bf16(            \
              af1[m], bf1[n], acc[m][n], 0, 0, 0);                        \
      __builtin_amdgcn_s_setprio(0);                                      \
    }

#define GBODY_N4(T_, BUF_, NTV, STAGE_MACRO)                              \
    if ((T_) + 1 < (NTV)) asm volatile("s_waitcnt vmcnt(8)" ::: "memory");\
    else                  asm volatile("s_waitcnt vmcnt(0)" ::: "memory");\
    __builtin_amdgcn_s_barrier();                                         \
    asm volatile("" ::: "memory");                                        \
    {                                                                     \
      bf16x8 af0[4], bf0[4], af1[4], bf1[4];                              \
      _Pragma("unroll") for (int m = 0; m < 4; m++) {                     \
        af0[m] = *(const bf16x8*)&As[BUF_][rowAo[m] + slt0];              \
        bf0[m] = *(const bf16x8*)&Bs[BUF_][rowBo[m] + slt0];              \
        af1[m] = *(const bf16x8*)&As[BUF_][rowAo[m] + slt1];              \
        bf1[m] = *(const bf16x8*)&Bs[BUF_][rowBo[m] + slt1];              \
      }                                                                   \
      asm volatile("s_waitcnt lgkmcnt(0)" ::: "memory");                  \
      __builtin_amdgcn_sched_barrier(0);                                  \
      __builtin_amdgcn_s_barrier();                                       \
      asm volatile("" ::: "memory");                                      \
      if ((T_) + 2 < (NTV)) STAGE_MACRO(BUF_, (T_) + 2);                  \
      __builtin_amdgcn_s_setprio(1);                                      \
      _Pragma("unroll") for (int m = 0; m < 4; m++)                       \
        _Pragma("unroll") for (int n = 0; n < 4; n++)                     \
          acc[m][n] = __builtin_amdgcn_mfma_f32_16x16x32_bf16(            \
              af0[m], bf0[n], acc[m][n], 0, 0, 0);                        \
      _Pragma("unroll") for (int m = 0; m < 4; m++)                       \
        _Pragma("unroll") for (int n = 0; n < 4; n++)                     \
          acc[m][n] = __builtin_amdgcn_mfma_f32_16x16x32_bf16(            \
              af1[m], bf1[n], acc[m][n], 0, 0, 0);                        \
      __builtin_amdgcn_s_setprio(0);                                      \
    }

// ---------------- GEMM1: H[p] = gelu(x[tok(p)]@W1[z]+b1)*gate ---------------
// 128x64 tiles, F=512 -> 8 bn. grid 8*G1_CAP, XCD-pinned. 3 blocks/CU.
__global__ __launch_bounds__(256, 3) void k_gemm1(
    const short* __restrict__ xb, const short* __restrict__ w1t,
    const float* __restrict__ eb1, const float* __restrict__ sb1,
    const int* __restrict__ meta, const int* __restrict__ tile_z,
    const int* __restrict__ tile_row, const int* __restrict__ pair_tok,
    const float* __restrict__ pair_gate, short* __restrict__ H) {
  const int l = blockIdx.x;
  const int xcd = l & 7;
  const int i = l >> 3;
  const int ntx = meta[48 + xcd];
  int slot, bn;
  if (i < ntx * 8) {
    slot = meta[40 + xcd] + (i >> 3); bn = i & 7;
  } else {
    int j = i - ntx * 8;
    if (j >= 128) return;
    int js = xcd * 128 + j;                // 1024 shared items, 128 per XCD
    slot = MAX_RT + (js >> 3); bn = js & 7;
  }
  const int z = tile_z[slot];
  const int row0 = tile_row[slot];
  __shared__ __align__(16) short As[2][8192];
  __shared__ __align__(16) short Bs[2][4096];
  const int tid = threadIdx.x;
  const int lane = tid & 63;
  const int wv = tid >> 6;
  const int wm = wv >> 1, wn = wv & 1;

  const short* asrc[4]; const short* bsrc[2];
  {
    const short* wb = w1t + (size_t)z * F_DIM * D_DIM;
    int shtok = 0;
    if (slot >= MAX_RT) {
      shtok = row0 - SH_BASE;
      if (shtok >= TOKENS) shtok -= TOKENS;
    }
    #pragma unroll
    for (int i2 = 0; i2 < 4; i2++) {
      int id = i2 * 256 + tid;
      int row = id >> 3, c = id & 7;
      int kc = ((c ^ (row & 7)) << 3);
      int arow = (slot < MAX_RT) ? pair_tok[row0 + row] : (shtok + row);
      asrc[i2] = xb + (size_t)arow * D_DIM + kc;
    }
    #pragma unroll
    for (int i2 = 0; i2 < 2; i2++) {
      int id = i2 * 256 + tid;
      int row = id >> 3, c = id & 7;     // row 0..63
      int kc = ((c ^ (row & 7)) << 3);
      bsrc[i2] = wb + (size_t)(bn * 64 + row) * D_DIM + kc;
    }
  }

  const int slt0 = (((lane >> 4)) ^ (lane & 7)) << 3;
  const int slt1 = ((4 + (lane >> 4)) ^ (lane & 7)) << 3;
  int rowAo[4], rowBo[2];
  #pragma unroll
  for (int m = 0; m < 4; m++)
    rowAo[m] = (wm * 64 + m * 16 + (lane & 15)) * 64;
  #pragma unroll
  for (int n = 0; n < 2; n++)
    rowBo[n] = (wn * 32 + n * 16 + (lane & 15)) * 64;

  f32x4 acc[4][2];
  #pragma unroll
  for (int m = 0; m < 4; m++)
    #pragma unroll
    for (int n = 0; n < 2; n++) acc[m][n] = (f32x4)(0.f);

  #define STAGE1(BUF, TT) do {                                            \
      int k0_ = (TT) * 64;                                                \
      _Pragma("unroll") for (int i2 = 0; i2 < 4; i2++)                    \
        gload_lds16(asrc[i2] + k0_, &As[BUF][(i2 * 256 + tid) * 8]);      \
      _Pragma("unroll") for (int i2 = 0; i2 < 2; i2++)                    \
        gload_lds16(bsrc[i2] + k0_, &Bs[BUF][(i2 * 256 + tid) * 8]);      \
    } while (0)

  STAGE1(0, 0);
  STAGE1(1, 1);

  const int NT = D_DIM / 64;   // 32 (even)
  for (int t = 0; t < NT; t += 2) {
    GBODY_N2(t,     0, NT, STAGE1);
    GBODY_N2(t + 1, 1, NT, STAGE1);
  }
  #undef STAGE1

  const float* b1 = (z < NE) ? (eb1 + z * F_DIM) : (sb1 + (size_t)(z - NE) * F_DIM);
  #pragma unroll
  for (int m = 0; m < 4; m++) {
    #pragma unroll
    for (int r = 0; r < 4; r++) {
      int row = wm * 64 + m * 16 + (lane >> 4) * 4 + r;
      float g = pair_gate[row0 + row];
      #pragma unroll
      for (int n = 0; n < 2; n++) {
        int col = bn * 64 + wn * 32 + n * 16 + (lane & 15);
        float c = acc[m][n][r] + b1[col];
        float h = 0.5f * c * (1.0f + erf_fast(c * 0.70710678118654752440f));
        H[(size_t)(row0 + row) * F_DIM + col] = f2bf(h * g);
      }
    }
  }
}

// ---------------- GEMM2 routed: Yr[p] = H[p] @ W2t[z]  (K=512) --------------
// 128x64 tiles, D=2048 -> 32 bn. grid 8*G2R_CAP. 3 blocks/CU.
__global__ __launch_bounds__(256, 3) void k_gemm2r(
    const short* __restrict__ Hb, const short* __restrict__ w2t,
    const int* __restrict__ meta, const int* __restrict__ tile_z,
    const int* __restrict__ tile_row, short* __restrict__ Yr) {
  const int l = blockIdx.x;
  const int xcd = l & 7;
  const int i = l >> 3;
  const int ntx = meta[48 + xcd];
  if (i >= ntx * 32) return;
  const int slot = meta[40 + xcd] + (i >> 5);
  const int bn = i & 31;
  const int z = tile_z[slot];
  const int row0 = tile_row[slot];
  __shared__ __align__(16) short As[2][8192];
  __shared__ __align__(16) short Bs[2][4096];
  const int tid = threadIdx.x;
  const int lane = tid & 63;
  const int wv = tid >> 6;
  const int wm = wv >> 1, wn = wv & 1;

  const short* asrc[4]; const short* bsrc[2];
  {
    const short* Bb = w2t + (size_t)z * D_DIM * F_DIM;
    #pragma unroll
    for (int i2 = 0; i2 < 4; i2++) {
      int id = i2 * 256 + tid;
      int row = id >> 3, c = id & 7;
      int kc = ((c ^ (row & 7)) << 3);
      asrc[i2] = Hb + (size_t)(row0 + row) * F_DIM + kc;
    }
    #pragma unroll
    for (int i2 = 0; i2 < 2; i2++) {
      int id = i2 * 256 + tid;
      int row = id >> 3, c = id & 7;
      int kc = ((c ^ (row & 7)) << 3);
      bsrc[i2] = Bb + (size_t)(bn * 64 + row) * F_DIM + kc;
    }
  }

  const int slt0 = (((lane >> 4)) ^ (lane & 7)) << 3;
  const int slt1 = ((4 + (lane >> 4)) ^ (lane & 7)) << 3;
  int rowAo[4], rowBo[2];
  #pragma unroll
  for (int m = 0; m < 4; m++)
    rowAo[m] = (wm * 64 + m * 16 + (lane & 15)) * 64;
  #pragma unroll
  for (int n = 0; n < 2; n++)
    rowBo[n] = (wn * 32 + n * 16 + (lane & 15)) * 64;

  f32x4 acc[4][2];
  #pragma unroll
  for (int m = 0; m < 4; m++)
    #pragma unroll
    for (int n = 0; n < 2; n++) acc[m][n] = (f32x4)(0.f);

  #define STAGE2R(BUF, TT) do {                                           \
      int k0_ = (TT) * 64;                                                \
      _Pragma("unroll") for (int i2 = 0; i2 < 4; i2++)                    \
        gload_lds16(asrc[i2] + k0_, &As[BUF][(i2 * 256 + tid) * 8]);      \
      _Pragma("unroll") for (int i2 = 0; i2 < 2; i2++)                    \
        gload_lds16(bsrc[i2] + k0_, &Bs[BUF][(i2 * 256 + tid) * 8]);      \
    } while (0)

  STAGE2R(0, 0);
  STAGE2R(1, 1);

  const int NT = F_DIM / 64;   // 8 (even)
  for (int t = 0; t < NT; t += 2) {
    GBODY_N2(t,     0, NT, STAGE2R);
    GBODY_N2(t + 1, 1, NT, STAGE2R);
  }
  #undef STAGE2R

  #pragma unroll
  for (int m = 0; m < 4; m++) {
    #pragma unroll
    for (int r = 0; r < 4; r++) {
      int row = wm * 64 + m * 16 + (lane >> 4) * 4 + r;
      #pragma unroll
      for (int n = 0; n < 2; n++) {
        int col = bn * 64 + wn * 32 + n * 16 + (lane & 15);
        Yr[(size_t)(row0 + row) * D_DIM + col] = f2bf(acc[m][n][r]);
      }
    }
  }
}

// -------- GEMM2 shared (K=1024) + fused combine: out = shared + biases + Yr -
// 128x128 tiles (perfect fill: 1024 items / 512 slots).
__global__ __launch_bounds__(256, 2) void k_gemm2s(
    const short* __restrict__ Hb, const short* __restrict__ w2t,
    const int2* __restrict__ ti, const float2* __restrict__ tg,
    const float* __restrict__ eb2, const float* __restrict__ sb2,
    const short* __restrict__ Yr, const int2* __restrict__ pos,
    float* __restrict__ out) {
  const int l = blockIdx.x;
  const int js = (l & 7) * 128 + (l >> 3);
  const int t0 = (js >> 4) * 128;
  const int bn = js & 15;
  __shared__ __align__(16) short As[2][8192];
  __shared__ __align__(16) short Bs[2][8192];
  const int tid = threadIdx.x;
  const int lane = tid & 63;
  const int wv = tid >> 6;
  const int wm = wv >> 1, wn = wv & 1;

  size_t aoff[4], boff[4];
  #pragma unroll
  for (int i2 = 0; i2 < 4; i2++) {
    int id = i2 * 256 + tid;
    int row = id >> 3, c = id & 7;
    int kc = ((c ^ (row & 7)) << 3);
    aoff[i2] = (size_t)row * F_DIM + kc;
    boff[i2] = (size_t)(bn * 128 + row) * F_DIM + kc;
  }
  const short* Abase0 = Hb + (size_t)(SH_BASE + t0) * F_DIM;
  const short* Bbase0 = w2t + (size_t)NE * D_DIM * F_DIM;

  const int slt0 = (((lane >> 4)) ^ (lane & 7)) << 3;
  const int slt1 = ((4 + (lane >> 4)) ^ (lane & 7)) << 3;
  int rowAo[4], rowBo[4];
  #pragma unroll
  for (int m = 0; m < 4; m++) {
    rowAo[m] = (wm * 64 + m * 16 + (lane & 15)) * 64;
    rowBo[m] = (wn * 64 + m * 16 + (lane & 15)) * 64;
  }

  f32x4 acc[4][4];
  #pragma unroll
  for (int m = 0; m < 4; m++)
    #pragma unroll
    for (int n = 0; n < 4; n++) acc[m][n] = (f32x4)(0.f);

  #define STAGE2S(BUF, TT) do {                                           \
      int kcol_ = ((TT) * 64) & (F_DIM - 1);                              \
      const short* Ab_ = Abase0;                                          \
      const short* Bb_ = Bbase0;                                          \
      if ((TT) >= 8) {                                                    \
        Ab_ += (size_t)TOKENS * F_DIM;                                    \
        Bb_ += (size_t)D_DIM * F_DIM;                                     \
      }                                                                   \
      _Pragma("unroll") for (int i2 = 0; i2 < 4; i2++) {                  \
        int id_ = i2 * 256 + tid;                                         \
        gload_lds16(Ab_ + aoff[i2] + kcol_, &As[BUF][id_ * 8]);           \
        gload_lds16(Bb_ + boff[i2] + kcol_, &Bs[BUF][id_ * 8]);           \
      }                                                                   \
    } while (0)

  STAGE2S(0, 0);
  STAGE2S(1, 1);

  const int NT = 16;
  for (int t = 0; t < NT; t += 2) {
    GBODY_N4(t,     0, NT, STAGE2S);
    GBODY_N4(t + 1, 1, NT, STAGE2S);
  }
  #undef STAGE2S

  #pragma unroll
  for (int m = 0; m < 4; m++) {
    #pragma unroll
    for (int r = 0; r < 4; r++) {
      int row = t0 + wm * 64 + m * 16 + (lane >> 4) * 4 + r;
      int2 ii = ti[row]; float2 gg = tg[row];
      int2 p = pos[row];
      #pragma unroll
      for (int n = 0; n < 4; n++) {
        int col = bn * 128 + wn * 64 + n * 16 + (lane & 15);
        float v = acc[m][n][r]
                + gg.x * eb2[(size_t)ii.x * D_DIM + col]
                + gg.y * eb2[(size_t)ii.y * D_DIM + col]
                + sb2[col] + sb2[D_DIM + col]
                + bf2f(Yr[(size_t)p.x * D_DIM + col])
                + bf2f(Yr[(size_t)p.y * D_DIM + col]);
        out[(size_t)row * D_DIM + col] = v;
      }
    }
  }
}

// ---------------------------------------------------------------------------
extern "C" void kernel_launch(void* const* d_in, const int* in_sizes, int n_in,
                              void* d_out, int out_size, void* d_ws, size_t ws_size,
                              hipStream_t stream) {
  (void)in_sizes; (void)n_in; (void)out_size; (void)ws_size;
  const float* x        = (const float*)d_in[0];
  const float* router_w = (const float*)d_in[1];
  const float* router_b = (const float*)d_in[2];
  const float* ew1      = (const float*)d_in[3];
  const float* eb1      = (const float*)d_in[4];
  const float* ew2      = (const float*)d_in[5];
  const float* eb2      = (const float*)d_in[6];
  const float* sw1      = (const float*)d_in[7];
  const float* sb1      = (const float*)d_in[8];
  const float* sw2      = (const float*)d_in[9];
  const float* sb2      = (const float*)d_in[10];
  float* out = (float*)d_out;

  // workspace layout (Yr aliases xb+w1t+overhang; dead after k_gemm1):
  //   w2t 20.97MB | Hbuf 34.6MB | small ~0.6MB | xb 33.55MB | w1t 20.97MB |
  //   Yr-overhang ~17MB  => total ~128MB
  char* ws = (char*)d_ws;
  short*  w2t       = (short*)ws;
  short*  Hbuf      = w2t + (size_t)NZ * D_DIM * F_DIM;
  int2*   ti        = (int2*)(Hbuf + (size_t)NPAIRS * F_DIM);
  float2* tg        = (float2*)(ti + TOKENS);
  int2*   pos       = (int2*)(tg + TOKENS);
  int*    pair_tok  = (int*)(pos + TOKENS);
  float*  pair_gate = (float*)(pair_tok + NPAIRS);
  int*    meta      = (int*)(pair_gate + NPAIRS);
  int*    tile_z    = meta + 64;
  int*    tile_row  = tile_z + 512;
  short*  xb        = (short*)(((uintptr_t)(tile_row + 512) + 255) & ~(uintptr_t)255);
  short*  w1t       = xb + (size_t)TOKENS * D_DIM;
  short*  Yr        = xb;   // alias (valid after k_gemm1 completes)

  k_prep<<<PREP_G, 256, 0, stream>>>(
      ew1, sw1, w1t, ew2, sw2, w2t,
      x, router_w, router_b, xb, ti, tg, pair_tok, pair_gate);
  k_count<<<1, 1024, 0, stream>>>(ti, meta, tile_z, tile_row, out + OUT_ELEMS);
  k_assign<<<TOKENS / 256, 256, 0, stream>>>(ti, tg, meta, pair_tok, pair_gate, pos);

  k_gemm1<<<8 * G1_CAP, 256, 0, stream>>>(
      xb, w1t, eb1, sb1, meta, tile_z, tile_row, pair_tok, pair_gate, Hbuf);
  k_gemm2r<<<8 * G2R_CAP, 256, 0, stream>>>(
      Hbuf, w2t, meta, tile_z, tile_row, Yr);
  k_gemm2s<<<1024, 256, 0, stream>>>(
      Hbuf, w2t, ti, tg, eb2, sb2, Yr, pos, out);
}